// Round 8
// baseline (587.075 us; speedup 1.0000x reference)
//
#include <hip/hip_runtime.h>
#include <math.h>

#define NB    4
#define NPTS  2048
#define ROWS  (NB*NPTS)   // 8192
#define CIN   64
#define COUT  256
#define KNBR  21
#define NHEADS 7
#define WCH   64
#define DSH   32

typedef __attribute__((ext_vector_type(8))) short short8;
typedef __attribute__((ext_vector_type(4))) float floatx4;

__device__ __forceinline__ ushort f2bf(float x) {
    unsigned u = __float_as_uint(x);
    u += 0x7fffu + ((u >> 16) & 1u);   // RNE
    return (ushort)(u >> 16);
}

// ---------------------------------------------------------------- geoBC (+ zero SUMS in blocks 0..11)
__global__ __launch_bounds__(256) void geoBC_kernel(const float* __restrict__ xyz, const float* __restrict__ Wg,
                                                    float* __restrict__ geoBC, float* __restrict__ sums) {
    if (blockIdx.x < 12) sums[blockIdx.x*256 + threadIdx.x] = 0.f;
    int i = blockIdx.x*256 + threadIdx.x;
    int p = i >> 8, c = i & 255, cc = c & 127;
    float x = xyz[p*3+0], y = xyz[p*3+1], z = xyz[p*3+2];
    const float* w = Wg + cc*6;
    float s;
    if (c < 128) s = (w[3]*x + w[4]*y) + w[5]*z;
    else         s = ((w[0]-w[3])*x + (w[1]-w[4])*y) + (w[2]-w[5])*z;
    geoBC[i] = s;
}

// ---------------------------------------------------------------- featAC as GEMM (A staged K-major from f)
__global__ __launch_bounds__(256) void gemm_feat(const float* __restrict__ f, const float* __restrict__ Wf,
                                                 float* __restrict__ X) {
    __shared__ float As[16][68];
    __shared__ float Ws[16][68];
    int t = threadIdx.x;
    int tx = t & 15, ty = t >> 4;
    int r0 = blockIdx.x * 64, n0 = blockIdx.y * 64;
    int b = r0 >> 11, nbase = r0 & 2047;
    float acc[4][4];
#pragma unroll
    for (int i = 0; i < 4; i++)
#pragma unroll
        for (int j = 0; j < 4; j++) acc[i][j] = 0.f;
    int m64 = t & 63, kg = t >> 6;
    int lk = t & 15, lm = t >> 4;
    for (int k0 = 0; k0 < 64; k0 += 16) {
#pragma unroll
        for (int p = 0; p < 4; p++) {
            int k = kg*4 + p;
            As[k][m64] = f[(size_t)b*CIN*NPTS + (size_t)(k0 + k)*NPTS + nbase + m64];
        }
#pragma unroll
        for (int i2 = 0; i2 < 4; i2++) {
            int cg = n0 + lm + 16*i2;
            Ws[lk][lm + 16*i2] = Wf[(size_t)(cg & 127)*128 + (cg >> 7)*64 + k0 + lk];
        }
        __syncthreads();
#pragma unroll
        for (int kq = 0; kq < 16; kq++) {
            float4 a  = *(const float4*)&As[kq][4*ty];
            float4 b4 = *(const float4*)&Ws[kq][4*tx];
            float av[4] = {a.x, a.y, a.z, a.w};
            float bv[4] = {b4.x, b4.y, b4.z, b4.w};
#pragma unroll
            for (int i = 0; i < 4; i++)
#pragma unroll
                for (int j = 0; j < 4; j++) acc[i][j] = fmaf(av[i], bv[j], acc[i][j]);
        }
        __syncthreads();
    }
#pragma unroll
    for (int i = 0; i < 4; i++)
#pragma unroll
        for (int j = 0; j < 4; j++)
            X[(size_t)(r0 + 4*ty + i)*256 + n0 + 4*tx + j] = acc[i][j];
}

// ---------------------------------------------------------------- KNN in FLOAT64 (exact ordering)
__global__ __launch_bounds__(256) void knn_kernel(const float* __restrict__ xyz, int* __restrict__ idx) {
    __shared__ float sx[NPTS*3];
    int blk = blockIdx.x;
    int b = blk >> 9;
    int g = blk & 511;
    int t = threadIdx.x;
    for (int i = t; i < NPTS*3; i += 256) sx[i] = xyz[(size_t)b*NPTS*3 + i];
    __syncthreads();
    int wave = t >> 6, lane = t & 63;
    int n = g*4 + wave;
    double qx = (double)sx[n*3], qy = (double)sx[n*3+1], qz = (double)sx[n*3+2];
    double sqn = qx*qx + qy*qy + qz*qz;
    double d[32];
#pragma unroll
    for (int i = 0; i < 32; i++) {
        int m = lane + (i << 6);
        double x = (double)sx[m*3], y = (double)sx[m*3+1], z = (double)sx[m*3+2];
        double sqm = x*x + y*y + z*z;
        double dt  = qx*x + qy*y + qz*z;
        d[i] = (sqn + sqm) - 2.0*dt;
    }
    double lv = d[0]; int li = 0;
#pragma unroll
    for (int i = 1; i < 32; i++) if (d[i] < lv) { lv = d[i]; li = i; }
    for (int kk = 0; kk < KNBR; kk++) {
        double bv = lv;
        unsigned bi = (unsigned)(lane + (li << 6));
        for (int off = 1; off < 64; off <<= 1) {
            double   ov = __shfl_xor(bv, off, 64);
            unsigned oi = __shfl_xor(bi, off, 64);
            if (ov < bv || (ov == bv && oi < bi)) { bv = ov; bi = oi; }
        }
        int m = (int)bi;
        if (lane == 0) idx[((size_t)b*NPTS + n)*KNBR + kk] = m;
        bool mine = ((m & 63) == lane);
        int slot = m >> 6;
#pragma unroll
        for (int i = 0; i < 32; i++) if (mine && slot == i) d[i] = INFINITY;
        if (mine) {
            lv = d[0]; li = 0;
#pragma unroll
            for (int i = 1; i < 32; i++) if (d[i] < lv) { lv = d[i]; li = i; }
        }
    }
}

// ---------------------------------------------------------------- stats + sign-selected extreme over K
__global__ __launch_bounds__(256) void stats_gf(const float* __restrict__ geoBC, const float* __restrict__ featAC,
                                                const int* __restrict__ idx, const float* __restrict__ g_geo,
                                                const float* __restrict__ g_feat,
                                                float* __restrict__ sums, float* __restrict__ xsel) {
    int c = threadIdx.x;
    int cc = c & 127;
    const float* base = (c < 128) ? geoBC : featAC;
    bool wantmax = ((c < 128) ? g_geo[cc] : g_feat[cc]) >= 0.f;
    float s = 0.f, ss = 0.f;
    int r0 = blockIdx.x * 32;
    for (int r = r0; r < r0 + 32; r++) {
        int b = r >> 11;
        float ctr = base[(size_t)r*256 + 128 + cc];
        float mx = -1e30f, mn = 1e30f;
        const int* ip = idx + (size_t)r*KNBR;
        for (int kk = 0; kk < KNBR; kk++) {
            int j = ip[kk];
            float xv = ctr + base[((size_t)(b*NPTS + j))*256 + cc];
            mx = fmaxf(mx, xv); mn = fminf(mn, xv);
            s += xv; ss += xv*xv;
        }
        xsel[(size_t)r*256 + c] = wantmax ? mx : mn;
    }
    atomicAdd(&sums[c], s);
    atomicAdd(&sums[256 + c], ss);
}

__global__ void bn_finalize_gf(const float* __restrict__ sums, const float* __restrict__ g_geo,
                               const float* __restrict__ b_geo, const float* __restrict__ g_feat,
                               const float* __restrict__ b_feat, float* __restrict__ st) {
    int c = threadIdx.x;
    const float inv = 1.0f / (float)(ROWS*KNBR);
    float mean = sums[c]*inv;
    float var  = sums[256+c]*inv - mean*mean;
    float g  = (c < 128) ? g_geo[c] : g_feat[c-128];
    float bb = (c < 128) ? b_geo[c] : b_feat[c-128];
    float s = g / sqrtf(var + 1e-5f);
    st[c] = s; st[256+c] = bb - mean*s;
}

__global__ void bn_finalize(const float* __restrict__ sums, const float* __restrict__ g,
                            const float* __restrict__ b, float* __restrict__ st, float inv_cnt) {
    int c = threadIdx.x;
    float mean = sums[c]*inv_cnt;
    float var  = sums[256+c]*inv_cnt - mean*mean;
    float s = g[c] / sqrtf(var + 1e-5f);
    st[c] = s; st[256+c] = b[c] - mean*s;
}

__global__ void bn_finalize_qkv(const float* __restrict__ sums, const float* __restrict__ g_q,
                                const float* __restrict__ b_q, const float* __restrict__ g_k,
                                const float* __restrict__ b_k, const float* __restrict__ g_v,
                                const float* __restrict__ b_v, float* __restrict__ st) {
    int c = threadIdx.x;            // 0..767
    int g = c >> 8, cc = c & 255;
    const float* S = sums + 1024 + g*512;
    float mean = S[cc] * (1.0f/(float)ROWS);
    float var  = S[256+cc] * (1.0f/(float)ROWS) - mean*mean;
    const float* gg = (g==0) ? g_q : (g==1) ? g_k : g_v;
    const float* bb = (g==0) ? b_q : (g==1) ? b_k : b_v;
    float s = gg[cc] / sqrtf(var + 1e-5f);
    float* T = st + 1024 + g*512;
    T[cc] = s; T[256+cc] = bb[cc] - mean*s;
}

// ---------------------------------------------------------------- feature_ = relu(affine(xsel)) ; + bn1 stats
__global__ __launch_bounds__(256) void feature_maxsel(const float* __restrict__ xsel, const float* __restrict__ st,
                                                      float* __restrict__ feat, float* __restrict__ sums_bn1) {
    int c = threadIdx.x;
    float sc = st[c], tt = st[256+c];
    float s = 0.f, ss = 0.f;
    int r0 = blockIdx.x*32;
    for (int r = r0; r < r0+32; r++) {
        size_t i = (size_t)r*256 + c;
        float y = fmaxf(fmaf(sc, xsel[i], tt), 0.f);
        feat[i] = y; s += y; ss += y*y;
    }
    atomicAdd(&sums_bn1[c], s); atomicAdd(&sums_bn1[256+c], ss);
}

// ---------------------------------------------------------------- merged q/k/v GEMM: affine-x on A-load, fp32 out, stats
__global__ __launch_bounds__(256) void gemm_qkv(const float* __restrict__ A, const float* __restrict__ bnst,
                                                const float* __restrict__ Wq, const float* __restrict__ Wk,
                                                const float* __restrict__ Wv,
                                                float* __restrict__ QKVF, float* __restrict__ sums) {
    __shared__ float As[16][68];
    __shared__ float Ws[16][68];
    __shared__ float red[4][64][2];
    int t = threadIdx.x;
    int tx = t & 15, ty = t >> 4;
    int r0 = blockIdx.x * 64, n0 = blockIdx.y * 64;
    int wsel = n0 >> 8, nrow0 = n0 & 255;
    const float* W = (wsel == 0) ? Wq : (wsel == 1) ? Wk : Wv;
    float acc[4][4];
#pragma unroll
    for (int i = 0; i < 4; i++)
#pragma unroll
        for (int j = 0; j < 4; j++) acc[i][j] = 0.f;
    int lk = t & 15, lm = t >> 4;
    for (int k0 = 0; k0 < 256; k0 += 16) {
        float sc = bnst[k0 + lk], sh = bnst[256 + k0 + lk];
#pragma unroll
        for (int i2 = 0; i2 < 4; i2++) {
            As[lk][lm + 16*i2] = fmaf(sc, A[(size_t)(r0 + lm + 16*i2)*256 + k0 + lk], sh);
            Ws[lk][lm + 16*i2] = W[(size_t)(nrow0 + lm + 16*i2)*256 + k0 + lk];
        }
        __syncthreads();
#pragma unroll
        for (int kq = 0; kq < 16; kq++) {
            float4 a  = *(const float4*)&As[kq][4*ty];
            float4 b4 = *(const float4*)&Ws[kq][4*tx];
            float av[4] = {a.x, a.y, a.z, a.w};
            float bv[4] = {b4.x, b4.y, b4.z, b4.w};
#pragma unroll
            for (int i = 0; i < 4; i++)
#pragma unroll
                for (int j = 0; j < 4; j++) acc[i][j] = fmaf(av[i], bv[j], acc[i][j]);
        }
        __syncthreads();
    }
    float ps[4], pss[4];
#pragma unroll
    for (int j = 0; j < 4; j++) { ps[j] = 0.f; pss[j] = 0.f; }
#pragma unroll
    for (int i = 0; i < 4; i++) {
#pragma unroll
        for (int j = 0; j < 4; j++) { ps[j] += acc[i][j]; pss[j] += acc[i][j]*acc[i][j]; }
        *(float4*)&QKVF[(size_t)(r0 + 4*ty + i)*768 + n0 + 4*tx] =
            make_float4(acc[i][0], acc[i][1], acc[i][2], acc[i][3]);
    }
#pragma unroll
    for (int j = 0; j < 4; j++) {
        ps[j]  += __shfl_xor(ps[j], 16, 64);  ps[j]  += __shfl_xor(ps[j], 32, 64);
        pss[j] += __shfl_xor(pss[j], 16, 64); pss[j] += __shfl_xor(pss[j], 32, 64);
    }
    int wv = t >> 6, lane = t & 63;
    if (lane < 16) {
#pragma unroll
        for (int j = 0; j < 4; j++) {
            red[wv][4*tx + j][0] = ps[j];
            red[wv][4*tx + j][1] = pss[j];
        }
    }
    __syncthreads();
    if (t < 128) {
        int col = t >> 1, which = t & 1;
        float v = red[0][col][which] + red[1][col][which] + red[2][col][which] + red[3][col][which];
        int g = n0 + col;
        atomicAdd(&sums[1024 + (g >> 8)*512 + which*256 + (g & 255)], v);
    }
}

// ---------------------------------------------------------------- affine+relu+bf16: q/k row-major, v transposed
__global__ __launch_bounds__(256) void affine_qkv(const float* __restrict__ QKVF, const float* __restrict__ st,
                                                  ushort* __restrict__ qk, ushort* __restrict__ vt) {
    __shared__ ushort tile[64][72];
    int t = threadIdx.x;
    int r0 = blockIdx.x * 64, c0 = blockIdx.y * 64;
    int b = r0 >> 11, nbase = r0 & 2047;
    if (c0 < 512) {
#pragma unroll
        for (int rep = 0; rep < 16; rep++) {
            int e = t + 256*rep;
            int row = e >> 6, c = e & 63;
            int col = c0 + c, g = col >> 8, cc = col & 255;
            float v = QKVF[(size_t)(r0 + row)*768 + col];
            v = fmaxf(fmaf(st[1024 + g*512 + cc], v, st[1024 + g*512 + 256 + cc]), 0.f);
            qk[(size_t)(r0 + row)*512 + col] = f2bf(v);
        }
    } else {
#pragma unroll
        for (int rep = 0; rep < 16; rep++) {
            int e = t + 256*rep;
            int row = e >> 6, c = e & 63;
            int col = c0 + c, cc = col & 255;
            float v = QKVF[(size_t)(r0 + row)*768 + col];
            v = fmaxf(fmaf(st[1024 + 2*512 + cc], v, st[1024 + 2*512 + 256 + cc]), 0.f);
            tile[c][row] = f2bf(v);
        }
        __syncthreads();
#pragma unroll
        for (int rep = 0; rep < 16; rep++) {
            int e = t + 256*rep;
            int cc = e >> 6, nn = e & 63;
            vt[((size_t)(b*256 + (c0 - 512) + cc))*2048 + nbase + nn] = tile[cc][nn];
        }
    }
}

// ---------------------------------------------------------------- split-K MFMA flash attention: 128 q-rows x 1024 keys
// outputs unnormalized O partial + per-row (m,l)
__global__ __launch_bounds__(256) void attn_split(const ushort* __restrict__ qk, const ushort* __restrict__ vt,
                                                  float* __restrict__ OP0, float* __restrict__ OP1,
                                                  float2* __restrict__ ML) {
    __shared__ ushort Ksh[64*72];
    __shared__ ushort Vts[64*72];
    __shared__ ushort Psh[128*72];
    int h = blockIdx.y;
    int z = blockIdx.z; int b = z >> 1, ks = z & 1;
    int r0 = blockIdx.x * 128;
    int t = threadIdx.x;
    int w = t >> 6, lane = t & 63;
    int r15 = lane & 15, quad = lane >> 4;
    size_t rowbase = (size_t)b*NPTS;
    int hoff = h*DSH;
    float* OP = ks ? OP1 : OP0;

    short8 aq[2][2];
#pragma unroll
    for (int u = 0; u < 2; u++)
#pragma unroll
        for (int s = 0; s < 2; s++)
            aq[u][s] = *(const short8*)(qk + (rowbase + r0 + 64*u + 16*w + r15)*512 + hoff + 32*s + 8*quad);

    floatx4 zero4 = {0.f, 0.f, 0.f, 0.f};
    floatx4 oacc[2][4];
    float mrun[2][4], lrun[2][4];
#pragma unroll
    for (int u = 0; u < 2; u++)
#pragma unroll
        for (int i = 0; i < 4; i++) { oacc[u][i] = zero4; mrun[u][i] = -1e30f; lrun[u][i] = 0.f; }

    int mstart = ks << 10;
    for (int m0 = mstart; m0 < mstart + 1024; m0 += 64) {
#pragma unroll
        for (int rep = 0; rep < 2; rep++) {
            int e = t + 256*rep;
            int rr = e >> 3, c = e & 7;
            *(uint4*)&Ksh[rr*72 + 8*c] =
                *(const uint4*)(qk + (rowbase + m0 + rr)*512 + 256 + hoff + 8*c);
            *(uint4*)&Vts[rr*72 + 8*c] =
                *(const uint4*)(vt + ((size_t)(b*256 + hoff + rr))*2048 + m0 + 8*c);
        }
        __syncthreads();

        floatx4 sacc[2][4];
#pragma unroll
        for (int u = 0; u < 2; u++)
#pragma unroll
            for (int tt = 0; tt < 4; tt++) sacc[u][tt] = zero4;
#pragma unroll
        for (int tt = 0; tt < 4; tt++) {
            int key = 16*tt + r15;
#pragma unroll
            for (int s = 0; s < 2; s++) {
                short8 kf = *(const short8*)&Ksh[key*72 + 32*s + 8*quad];
#pragma unroll
                for (int u = 0; u < 2; u++)
                    sacc[u][tt] = __builtin_amdgcn_mfma_f32_16x16x32_bf16(aq[u][s], kf, sacc[u][tt], 0, 0, 0);
            }
        }

        float pm[2][4][4];
#pragma unroll
        for (int u = 0; u < 2; u++)
#pragma unroll
            for (int reg = 0; reg < 4; reg++) {
                float rmax = fmaxf(fmaxf(sacc[u][0][reg], sacc[u][1][reg]),
                                   fmaxf(sacc[u][2][reg], sacc[u][3][reg]));
#pragma unroll
                for (int msk = 1; msk < 16; msk <<= 1) rmax = fmaxf(rmax, __shfl_xor(rmax, msk, 64));
                float mnew = fmaxf(mrun[u][reg], rmax);
                float alpha = __expf(mrun[u][reg] - mnew);
                float rs = 0.f;
#pragma unroll
                for (int tt = 0; tt < 4; tt++) {
                    float p = __expf(sacc[u][tt][reg] - mnew);
                    pm[u][tt][reg] = p; rs += p;
                }
#pragma unroll
                for (int msk = 1; msk < 16; msk <<= 1) rs += __shfl_xor(rs, msk, 64);
                lrun[u][reg] = lrun[u][reg]*alpha + rs;
                mrun[u][reg] = mnew;
#pragma unroll
                for (int td = 0; td < 4; td++) oacc[u][td][reg] *= alpha;
            }

#pragma unroll
        for (int u = 0; u < 2; u++)
#pragma unroll
            for (int reg = 0; reg < 4; reg++) {
                int row = 64*u + 16*w + 4*quad + reg;
#pragma unroll
                for (int tt = 0; tt < 4; tt++)
                    Psh[row*72 + 16*tt + r15] = f2bf(pm[u][tt][reg]);
            }
        __syncthreads();

#pragma unroll
        for (int s = 0; s < 2; s++) {
            short8 pf[2];
#pragma unroll
            for (int u = 0; u < 2; u++)
                pf[u] = *(const short8*)&Psh[(64*u + 16*w + r15)*72 + 32*s + 8*quad];
#pragma unroll
            for (int td = 0; td < 4; td++) {
                short8 vf = *(const short8*)&Vts[(16*td + r15)*72 + 32*s + 8*quad];
#pragma unroll
                for (int u = 0; u < 2; u++)
                    oacc[u][td] = __builtin_amdgcn_mfma_f32_16x16x32_bf16(pf[u], vf, oacc[u][td], 0, 0, 0);
            }
        }
        __syncthreads();
    }

    // epilogue: unnormalized partial + (m,l)
#pragma unroll
    for (int u = 0; u < 2; u++)
#pragma unroll
        for (int reg = 0; reg < 4; reg++) {
            int grow = r0 + 64*u + 16*w + 4*quad + reg;
#pragma unroll
            for (int td = 0; td < 4; td++)
                OP[(rowbase + grow)*(size_t)(NHEADS*WCH) + h*WCH + 16*td + r15] = oacc[u][td][reg];
            if (r15 == 0)
                ML[((size_t)ks*ROWS + rowbase + grow)*NHEADS + h] = make_float2(mrun[u][reg], lrun[u][reg]);
        }
}

// ---------------------------------------------------------------- (m,l) pairs -> merge weights
__global__ void w2_kernel(const float2* __restrict__ ML, float2* __restrict__ W2) {
    int idx = blockIdx.x*256 + threadIdx.x;    // 8192*7 = 57344
    float2 a = ML[idx];
    float2 c = ML[(size_t)ROWS*NHEADS + idx];
    float mm = fmaxf(a.x, c.x);
    float e0 = __expf(a.x - mm), e1 = __expf(c.x - mm);
    float inv = 1.f / (a.y*e0 + c.y*e1);
    W2[idx] = make_float2(e0*inv, e1*inv);
}

// ---------------------------------------------------------------- fus GEMM; A = merged attention partials
__global__ __launch_bounds__(256) void gemm_fus(const float* __restrict__ OP0, const float* __restrict__ OP1,
                                                const float2* __restrict__ W2, const float* __restrict__ W,
                                                const float* __restrict__ bias, float* __restrict__ C,
                                                float* __restrict__ sums) {
    __shared__ float As[16][68];
    __shared__ float Ws[16][68];
    __shared__ float red[4][64][2];
    int t = threadIdx.x;
    int tx = t & 15, ty = t >> 4;
    int r0 = blockIdx.x * 64, n0 = blockIdx.y * 64;
    float acc[4][4];
#pragma unroll
    for (int i = 0; i < 4; i++)
#pragma unroll
        for (int j = 0; j < 4; j++) acc[i][j] = 0.f;
    int lk = t & 15, lm = t >> 4;
    for (int k0 = 0; k0 < 448; k0 += 16) {
        int kk2 = k0 + lk;
        int h = kk2 >> 6;
#pragma unroll
        for (int i2 = 0; i2 < 4; i2++) {
            int row = r0 + lm + 16*i2;
            float2 wgt = W2[(size_t)row*NHEADS + h];
            As[lk][lm + 16*i2] = OP0[(size_t)row*448 + kk2]*wgt.x + OP1[(size_t)row*448 + kk2]*wgt.y;
            Ws[lk][lm + 16*i2] = W[(size_t)(n0 + lm + 16*i2)*448 + kk2];
        }
        __syncthreads();
#pragma unroll
        for (int kq = 0; kq < 16; kq++) {
            float4 a  = *(const float4*)&As[kq][4*ty];
            float4 b4 = *(const float4*)&Ws[kq][4*tx];
            float av[4] = {a.x, a.y, a.z, a.w};
            float bv[4] = {b4.x, b4.y, b4.z, b4.w};
#pragma unroll
            for (int i = 0; i < 4; i++)
#pragma unroll
                for (int j = 0; j < 4; j++) acc[i][j] = fmaf(av[i], bv[j], acc[i][j]);
        }
        __syncthreads();
    }
    float ps[4], pss[4];
#pragma unroll
    for (int j = 0; j < 4; j++) { ps[j] = 0.f; pss[j] = 0.f; }
#pragma unroll
    for (int i = 0; i < 4; i++)
#pragma unroll
        for (int j = 0; j < 4; j++) {
            float v = acc[i][j] + bias[n0 + 4*tx + j];
            C[(size_t)(r0 + 4*ty + i)*256 + n0 + 4*tx + j] = v;
            ps[j] += v; pss[j] += v*v;
        }
#pragma unroll
    for (int j = 0; j < 4; j++) {
        ps[j]  += __shfl_xor(ps[j], 16, 64);  ps[j]  += __shfl_xor(ps[j], 32, 64);
        pss[j] += __shfl_xor(pss[j], 16, 64); pss[j] += __shfl_xor(pss[j], 32, 64);
    }
    int wv = t >> 6, lane = t & 63;
    if (lane < 16) {
#pragma unroll
        for (int j = 0; j < 4; j++) {
            red[wv][4*tx + j][0] = ps[j];
            red[wv][4*tx + j][1] = pss[j];
        }
    }
    __syncthreads();
    if (t < 128) {
        int col = t >> 1, which = t & 1;
        float v = red[0][col][which] + red[1][col][which] + red[2][col][which] + red[3][col][which];
        atomicAdd(&sums[2560 + which*256 + n0 + col], v);
    }
}

// ---------------------------------------------------------------- fused: fus-affine+relu + residual + LayerNorm
__global__ __launch_bounds__(256) void ln_fused(float* __restrict__ fusp, const float* __restrict__ feature,
                                                const float* __restrict__ st,
                                                const float* __restrict__ g_ln, const float* __restrict__ b_ln,
                                                float* __restrict__ y) {
    int r = blockIdx.x, c = threadIdx.x;
    size_t i = (size_t)r*256 + c;
    float fus = fmaxf(fmaf(st[2560 + c], fusp[i], st[2560 + 256 + c]), 0.f);
    float v = fus + feature[i];
    float s = v, ss = v*v;
    for (int m = 1; m < 64; m <<= 1) { s += __shfl_xor(s, m, 64); ss += __shfl_xor(ss, m, 64); }
    __shared__ float red[8];
    int wave = c >> 6, lane = c & 63;
    if (lane == 0) { red[wave] = s; red[4+wave] = ss; }
    __syncthreads();
    s  = red[0]+red[1]+red[2]+red[3];
    ss = red[4]+red[5]+red[6]+red[7];
    float mean = s * (1.f/256.f);
    float var  = ss * (1.f/256.f) - mean*mean;
    float rin  = 1.f/sqrtf(var + 1e-5f);
    fusp[i] = v;
    y[i] = (v - mean)*rin*g_ln[c] + b_ln[c];
}

// ---------------------------------------------------------------- MLP GEMM + residual + transposed store to d_out
__global__ __launch_bounds__(256) void gemm_mlp(const float* __restrict__ A, const float* __restrict__ W,
                                                const float* __restrict__ bias, const float* __restrict__ FF,
                                                float* __restrict__ outp) {
    __shared__ float As[16][68];
    __shared__ float Ws[16][68];
    __shared__ float tr[64][65];
    int t = threadIdx.x;
    int tx = t & 15, ty = t >> 4;
    int r0 = blockIdx.x * 64, n0 = blockIdx.y * 64;
    float acc[4][4];
#pragma unroll
    for (int i = 0; i < 4; i++)
#pragma unroll
        for (int j = 0; j < 4; j++) acc[i][j] = 0.f;
    int lk = t & 15, lm = t >> 4;
    for (int k0 = 0; k0 < 256; k0 += 16) {
#pragma unroll
        for (int i2 = 0; i2 < 4; i2++) {
            As[lk][lm + 16*i2] = A[(size_t)(r0 + lm + 16*i2)*256 + k0 + lk];
            Ws[lk][lm + 16*i2] = W[(size_t)(n0 + lm + 16*i2)*256 + k0 + lk];
        }
        __syncthreads();
#pragma unroll
        for (int kq = 0; kq < 16; kq++) {
            float4 a  = *(const float4*)&As[kq][4*ty];
            float4 b4 = *(const float4*)&Ws[kq][4*tx];
            float av[4] = {a.x, a.y, a.z, a.w};
            float bv[4] = {b4.x, b4.y, b4.z, b4.w};
#pragma unroll
            for (int i = 0; i < 4; i++)
#pragma unroll
                for (int j = 0; j < 4; j++) acc[i][j] = fmaf(av[i], bv[j], acc[i][j]);
        }
        __syncthreads();
    }
#pragma unroll
    for (int i = 0; i < 4; i++)
#pragma unroll
        for (int j = 0; j < 4; j++) {
            float v = acc[i][j] + bias[n0 + 4*tx + j] + FF[(size_t)(r0 + 4*ty + i)*256 + n0 + 4*tx + j];
            tr[4*tx + j][4*ty + i] = v;
        }
    __syncthreads();
    int b = r0 >> 11, nbase = r0 & 2047;
#pragma unroll
    for (int rep = 0; rep < 16; rep++) {
        int e = t + 256*rep;
        int cl = e >> 6, nl = e & 63;
        outp[((size_t)(b*256 + n0 + cl))*2048 + nbase + nl] = tr[cl][nl];
    }
}

// ================================================================ host
extern "C" void kernel_launch(void* const* d_in, const int* in_sizes, int n_in,
                              void* d_out, int out_size, void* d_ws, size_t ws_size,
                              hipStream_t stream) {
    const float* xyz    = (const float*)d_in[0];
    const float* f      = (const float*)d_in[1];
    const float* W_geo  = (const float*)d_in[2];
    const float* g_geo  = (const float*)d_in[3];
    const float* b_geo  = (const float*)d_in[4];
    const float* W_feat = (const float*)d_in[5];
    const float* g_feat = (const float*)d_in[6];
    const float* b_feat = (const float*)d_in[7];
    const float* g_bn   = (const float*)d_in[8];
    const float* b_bn   = (const float*)d_in[9];
    const float* W_q    = (const float*)d_in[10];
    const float* g_q    = (const float*)d_in[11];
    const float* b_q    = (const float*)d_in[12];
    const float* W_k    = (const float*)d_in[13];
    const float* g_k    = (const float*)d_in[14];
    const float* b_k    = (const float*)d_in[15];
    const float* W_v    = (const float*)d_in[16];
    const float* g_v    = (const float*)d_in[17];
    const float* b_v    = (const float*)d_in[18];
    const float* W_fus  = (const float*)d_in[19];
    const float* bias_fus = (const float*)d_in[20];
    const float* g_fus  = (const float*)d_in[21];
    const float* b_fus  = (const float*)d_in[22];
    const float* g_ln   = (const float*)d_in[23];
    const float* b_ln   = (const float*)d_in[24];
    const float* W_mlp  = (const float*)d_in[25];
    const float* bias_mlp = (const float*)d_in[26];

    float* ws = (float*)d_ws;
    const size_t MBF = 262144;  // floats per MiB
    // Liveness (peak ~50.5 MiB):
    //  [0,1)    SUMS / ST / IDX
    //  [1,9)    A: geoBC -> feature_ (live until ln_fused)
    //  [25,33)  X (featAC; dead after stats_gf)
    //  [33,41)  CSEL (dead after maxsel)
    //  [25,49)  QKVF fp32 [8192x768] (over dead X/CSEL; dead after affine_qkv)
    //  [9,17)   QK16 bf16 (live through attn) -> FUSP fp32 after attn
    //  [17,21)  VT16 bf16 (live through attn) -> YB [17,25) after gemm_fus
    //  [21,35)  OP0 fp32 (over dead QKVF tail; live attn -> gemm_fus)
    //  [35,49)  OP1 fp32
    //  [49,~49.9)  ML (2*8192*7 float2)
    //  [50,~50.45) W2 (8192*7 float2)
    float* SUMS  = ws;
    float* ST    = ws + 4096;
    int*   IDX   = (int*)(ws + 16384);
    float* A     = ws + 1*MBF;
    float* X     = ws + 25*MBF;
    float* CSEL  = ws + 33*MBF;
    float* QKVF  = ws + 25*MBF;
    ushort* QK16 = (ushort*)(ws + 9*MBF);
    ushort* VT16 = (ushort*)(ws + 17*MBF);
    float* OP0   = ws + 21*MBF;
    float* OP1   = ws + 35*MBF;
    float2* ML   = (float2*)(ws + 49*MBF);
    float2* W2   = (float2*)(ws + 50*MBF);
    float* FUSP  = ws + 9*MBF;
    float* YB    = ws + 17*MBF;

    float* S_GF  = SUMS;        float* T_GF  = ST;
    float* S_BN1 = SUMS + 512;  float* T_BN1 = ST + 512;

    geoBC_kernel<<<ROWS, 256, 0, stream>>>(xyz, W_geo, A, SUMS);
    gemm_feat<<<dim3(128, 4), 256, 0, stream>>>(f, W_feat, X);
    knn_kernel<<<ROWS/4, 256, 0, stream>>>(xyz, IDX);

    stats_gf<<<256, 256, 0, stream>>>(A, X, IDX, g_geo, g_feat, S_GF, CSEL);
    bn_finalize_gf<<<1, 256, 0, stream>>>(S_GF, g_geo, b_geo, g_feat, b_feat, T_GF);
    feature_maxsel<<<256, 256, 0, stream>>>(CSEL, T_GF, A, S_BN1);
    bn_finalize<<<1, 256, 0, stream>>>(S_BN1, g_bn, b_bn, T_BN1, 1.0f/(float)ROWS);

    gemm_qkv<<<dim3(128, 12), 256, 0, stream>>>(A, T_BN1, W_q, W_k, W_v, QKVF, SUMS);
    bn_finalize_qkv<<<1, 768, 0, stream>>>(SUMS, g_q, b_q, g_k, b_k, g_v, b_v, ST);
    affine_qkv<<<dim3(128, 12), 256, 0, stream>>>(QKVF, ST, QK16, VT16);

    attn_split<<<dim3(NPTS/128, NHEADS, NB*2), 256, 0, stream>>>(QK16, VT16, OP0, OP1, ML);
    w2_kernel<<<ROWS*NHEADS/256, 256, 0, stream>>>(ML, W2);

    gemm_fus<<<dim3(128, 4), 256, 0, stream>>>(OP0, OP1, W2, W_fus, bias_fus, FUSP, SUMS);
    bn_finalize<<<1, 256, 0, stream>>>(SUMS + 2560, g_fus, b_fus, ST + 2560, 1.0f/(float)ROWS);
    ln_fused<<<ROWS, 256, 0, stream>>>(FUSP, A, ST, g_ln, b_ln, YB);
    gemm_mlp<<<dim3(128, 4), 256, 0, stream>>>(YB, W_mlp, bias_mlp, FUSP, (float*)d_out);
}

// Round 9
// 500.975 us; speedup vs baseline: 1.1719x; 1.1719x over previous
//
#include <hip/hip_runtime.h>
#include <math.h>

#define NB    4
#define NPTS  2048
#define ROWS  (NB*NPTS)   // 8192
#define CIN   64
#define COUT  256
#define KNBR  21
#define NHEADS 7
#define WCH   64
#define DSH   32

typedef __attribute__((ext_vector_type(8))) short short8;
typedef __attribute__((ext_vector_type(4))) float floatx4;

__device__ __forceinline__ ushort f2bf(float x) {
    unsigned u = __float_as_uint(x);
    u += 0x7fffu + ((u >> 16) & 1u);   // RNE
    return (ushort)(u >> 16);
}

// DPP rotate within 16-lane row (VALU, no LDS pipe) — for reductions over r15 groups
template<int N>
__device__ __forceinline__ float dpp_ror16(float x) {
    return __int_as_float(__builtin_amdgcn_update_dpp(
        0, __float_as_int(x), 0x120 | N, 0xF, 0xF, true));
}
__device__ __forceinline__ float dpp_max16(float x) {
    x = fmaxf(x, dpp_ror16<1>(x));
    x = fmaxf(x, dpp_ror16<2>(x));
    x = fmaxf(x, dpp_ror16<4>(x));
    x = fmaxf(x, dpp_ror16<8>(x));
    return x;
}
__device__ __forceinline__ float dpp_sum16(float x) {
    x += dpp_ror16<1>(x);
    x += dpp_ror16<2>(x);
    x += dpp_ror16<4>(x);
    x += dpp_ror16<8>(x);
    return x;
}

// ---------------------------------------------------------------- prep: featAC GEMM + geoBC + W->bf16 + zero SUMS
__global__ __launch_bounds__(256) void prep_kernel(const float* __restrict__ f, const float* __restrict__ Wf,
                                                   const float* __restrict__ xyz, const float* __restrict__ Wg,
                                                   const float* __restrict__ W_q, const float* __restrict__ W_k,
                                                   const float* __restrict__ W_v,
                                                   float* __restrict__ X, float* __restrict__ A,
                                                   ushort* __restrict__ Wb, float* __restrict__ sums) {
    __shared__ float As[16][68];
    __shared__ float Ws[16][68];
    int t = threadIdx.x;
    int bx = blockIdx.x, by = blockIdx.y;
    if (by == 0 && bx < 12) sums[bx*256 + t] = 0.f;
    int gid = (by*128 + bx)*256 + t;   // 0..131071
    for (int i = gid; i < 196608; i += 131072) {
        const float* Wsrc = (i < 65536) ? W_q : (i < 131072) ? W_k : W_v;
        Wb[i] = f2bf(Wsrc[i & 65535]);
    }
    int r0 = bx * 64, n0 = by * 64;
    // geoBC for rows r0..+63, cols n0..+63
    for (int e = t; e < 4096; e += 256) {
        int row = r0 + (e >> 6), c = n0 + (e & 63), cc = c & 127;
        float x = xyz[row*3], y = xyz[row*3+1], z = xyz[row*3+2];
        const float* w = Wg + cc*6;
        float s = (c < 128) ? ((w[3]*x + w[4]*y) + w[5]*z)
                            : (((w[0]-w[3])*x + (w[1]-w[4])*y) + (w[2]-w[5])*z);
        A[(size_t)row*256 + c] = s;
    }
    // featAC GEMM
    int b = r0 >> 11, nbase = r0 & 2047;
    int tx = t & 15, ty = t >> 4;
    float acc[4][4];
#pragma unroll
    for (int i = 0; i < 4; i++)
#pragma unroll
        for (int j = 0; j < 4; j++) acc[i][j] = 0.f;
    int m64 = t & 63, kg = t >> 6;
    int lk = t & 15, lm = t >> 4;
    for (int k0 = 0; k0 < 64; k0 += 16) {
#pragma unroll
        for (int p = 0; p < 4; p++) {
            int k = kg*4 + p;
            As[k][m64] = f[(size_t)b*CIN*NPTS + (size_t)(k0 + k)*NPTS + nbase + m64];
        }
#pragma unroll
        for (int i2 = 0; i2 < 4; i2++) {
            int cg = n0 + lm + 16*i2;
            Ws[lk][lm + 16*i2] = Wf[(size_t)(cg & 127)*128 + (cg >> 7)*64 + k0 + lk];
        }
        __syncthreads();
#pragma unroll
        for (int kq = 0; kq < 16; kq++) {
            float4 a  = *(const float4*)&As[kq][4*ty];
            float4 b4 = *(const float4*)&Ws[kq][4*tx];
            float av[4] = {a.x, a.y, a.z, a.w};
            float bv[4] = {b4.x, b4.y, b4.z, b4.w};
#pragma unroll
            for (int i = 0; i < 4; i++)
#pragma unroll
                for (int j = 0; j < 4; j++) acc[i][j] = fmaf(av[i], bv[j], acc[i][j]);
        }
        __syncthreads();
    }
#pragma unroll
    for (int i = 0; i < 4; i++)
#pragma unroll
        for (int j = 0; j < 4; j++)
            X[(size_t)(r0 + 4*ty + i)*256 + n0 + 4*tx + j] = acc[i][j];
}

// ---------------------------------------------------------------- KNN in FLOAT64 (exact ordering)
__global__ __launch_bounds__(256) void knn_kernel(const float* __restrict__ xyz, int* __restrict__ idx) {
    __shared__ float sx[NPTS*3];
    int blk = blockIdx.x;
    int b = blk >> 9;
    int g = blk & 511;
    int t = threadIdx.x;
    for (int i = t; i < NPTS*3; i += 256) sx[i] = xyz[(size_t)b*NPTS*3 + i];
    __syncthreads();
    int wave = t >> 6, lane = t & 63;
    int n = g*4 + wave;
    double qx = (double)sx[n*3], qy = (double)sx[n*3+1], qz = (double)sx[n*3+2];
    double sqn = qx*qx + qy*qy + qz*qz;
    double d[32];
#pragma unroll
    for (int i = 0; i < 32; i++) {
        int m = lane + (i << 6);
        double x = (double)sx[m*3], y = (double)sx[m*3+1], z = (double)sx[m*3+2];
        double sqm = x*x + y*y + z*z;
        double dt  = qx*x + qy*y + qz*z;
        d[i] = (sqn + sqm) - 2.0*dt;
    }
    double lv = d[0]; int li = 0;
#pragma unroll
    for (int i = 1; i < 32; i++) if (d[i] < lv) { lv = d[i]; li = i; }
    for (int kk = 0; kk < KNBR; kk++) {
        double bv = lv;
        unsigned bi = (unsigned)(lane + (li << 6));
        for (int off = 1; off < 64; off <<= 1) {
            double   ov = __shfl_xor(bv, off, 64);
            unsigned oi = __shfl_xor(bi, off, 64);
            if (ov < bv || (ov == bv && oi < bi)) { bv = ov; bi = oi; }
        }
        int m = (int)bi;
        if (lane == 0) idx[((size_t)b*NPTS + n)*KNBR + kk] = m;
        bool mine = ((m & 63) == lane);
        int slot = m >> 6;
#pragma unroll
        for (int i = 0; i < 32; i++) if (mine && slot == i) d[i] = INFINITY;
        if (mine) {
            lv = d[0]; li = 0;
#pragma unroll
            for (int i = 1; i < 32; i++) if (d[i] < lv) { lv = d[i]; li = i; }
        }
    }
}

// ---------------------------------------------------------------- stats + sign-selected extreme over K
__global__ __launch_bounds__(256) void stats_gf(const float* __restrict__ geoBC, const float* __restrict__ featAC,
                                                const int* __restrict__ idx, const float* __restrict__ g_geo,
                                                const float* __restrict__ g_feat,
                                                float* __restrict__ sums, float* __restrict__ xsel) {
    int c = threadIdx.x;
    int cc = c & 127;
    const float* base = (c < 128) ? geoBC : featAC;
    bool wantmax = ((c < 128) ? g_geo[cc] : g_feat[cc]) >= 0.f;
    float s = 0.f, ss = 0.f;
    int r0 = blockIdx.x * 32;
    for (int r = r0; r < r0 + 32; r++) {
        int b = r >> 11;
        float ctr = base[(size_t)r*256 + 128 + cc];
        float mx = -1e30f, mn = 1e30f;
        const int* ip = idx + (size_t)r*KNBR;
        for (int kk = 0; kk < KNBR; kk++) {
            int j = ip[kk];
            float xv = ctr + base[((size_t)(b*NPTS + j))*256 + cc];
            mx = fmaxf(mx, xv); mn = fminf(mn, xv);
            s += xv; ss += xv*xv;
        }
        xsel[(size_t)r*256 + c] = wantmax ? mx : mn;
    }
    atomicAdd(&sums[c], s);
    atomicAdd(&sums[256 + c], ss);
}

// ---------------------------------------------------------------- feature_ = relu(affine(xsel)) with inline BN finalize; + bn1 stats
__global__ __launch_bounds__(256) void feature_maxsel(const float* __restrict__ xsel, const float* __restrict__ sums,
                                                      const float* __restrict__ g_geo, const float* __restrict__ b_geo,
                                                      const float* __restrict__ g_feat, const float* __restrict__ b_feat,
                                                      float* __restrict__ feat, float* __restrict__ sums_bn1) {
    int c = threadIdx.x;
    const float inv = 1.0f / (float)(ROWS*KNBR);
    float mean = sums[c]*inv;
    float var  = sums[256+c]*inv - mean*mean;
    float g  = (c < 128) ? g_geo[c] : g_feat[c-128];
    float bb = (c < 128) ? b_geo[c] : b_feat[c-128];
    float sc = g / sqrtf(var + 1e-5f);
    float tt = bb - mean*sc;
    float s = 0.f, ss = 0.f;
    int r0 = blockIdx.x*32;
    for (int r = r0; r < r0+32; r++) {
        size_t i = (size_t)r*256 + c;
        float y = fmaxf(fmaf(sc, xsel[i], tt), 0.f);
        feat[i] = y; s += y; ss += y*y;
    }
    atomicAdd(&sums_bn1[c], s); atomicAdd(&sums_bn1[256+c], ss);
}

// ---------------------------------------------------------------- q/k/v GEMM via bf16 MFMA; inline bn1 finalize on A;
// fp32 out + exact stats.  grid (128 Mtiles, 3 groups)
__global__ __launch_bounds__(256) void gemm_qkv(const float* __restrict__ Af, const float* __restrict__ sums_in,
                                                const float* __restrict__ g_bn, const float* __restrict__ b_bn,
                                                const ushort* __restrict__ Wb,
                                                float* __restrict__ QKVF, float* __restrict__ sums) {
    __shared__ float bns[2][256];
    __shared__ float red[4][256][2];
    int t = threadIdx.x;
    int r0 = blockIdx.x * 64, g = blockIdx.y;
    int w = t >> 6, lane = t & 63;
    int r15 = lane & 15, quad = lane >> 4;
    {
        float mean = sums_in[512 + t] * (1.0f/(float)ROWS);
        float var  = sums_in[768 + t] * (1.0f/(float)ROWS) - mean*mean;
        float sc = g_bn[t] / sqrtf(var + 1e-5f);
        bns[0][t] = sc;
        bns[1][t] = b_bn[t] - mean*sc;
    }
    __syncthreads();
    // A fragments: rows r0+16w+r15, bf16 after affine
    short8 aq[8];
    {
        const float* ap = Af + (size_t)(r0 + 16*w + r15)*256;
#pragma unroll
        for (int kc = 0; kc < 8; kc++) {
            int k0 = 32*kc + 8*quad;
            float4 a0 = *(const float4*)&ap[k0];
            float4 a1 = *(const float4*)&ap[k0+4];
            float4 s0 = *(const float4*)&bns[0][k0];
            float4 s1 = *(const float4*)&bns[0][k0+4];
            float4 h0 = *(const float4*)&bns[1][k0];
            float4 h1 = *(const float4*)&bns[1][k0+4];
            ushort u8[8];
            u8[0] = f2bf(fmaf(s0.x, a0.x, h0.x)); u8[1] = f2bf(fmaf(s0.y, a0.y, h0.y));
            u8[2] = f2bf(fmaf(s0.z, a0.z, h0.z)); u8[3] = f2bf(fmaf(s0.w, a0.w, h0.w));
            u8[4] = f2bf(fmaf(s1.x, a1.x, h1.x)); u8[5] = f2bf(fmaf(s1.y, a1.y, h1.y));
            u8[6] = f2bf(fmaf(s1.z, a1.z, h1.z)); u8[7] = f2bf(fmaf(s1.w, a1.w, h1.w));
            aq[kc] = *(short8*)u8;
        }
    }
    floatx4 zero4 = {0.f, 0.f, 0.f, 0.f};
    floatx4 acc[16];
#pragma unroll
    for (int st = 0; st < 16; st++) acc[st] = zero4;
    const ushort* wbase = Wb + (size_t)g*65536 + (size_t)r15*256 + 8*quad;
#pragma unroll
    for (int st = 0; st < 16; st++) {
        const ushort* wp = wbase + (size_t)(16*st)*256;
#pragma unroll
        for (int kc = 0; kc < 8; kc++) {
            short8 bf = *(const short8*)(wp + 32*kc);
            acc[st] = __builtin_amdgcn_mfma_f32_16x16x32_bf16(aq[kc], bf, acc[st], 0, 0, 0);
        }
    }
    // store fp32 + stats
#pragma unroll
    for (int st = 0; st < 16; st++) {
        float s  = (acc[st][0] + acc[st][1]) + (acc[st][2] + acc[st][3]);
        float q2 = (acc[st][0]*acc[st][0] + acc[st][1]*acc[st][1]) +
                   (acc[st][2]*acc[st][2] + acc[st][3]*acc[st][3]);
        s  += __shfl_xor(s, 16, 64);  s  += __shfl_xor(s, 32, 64);
        q2 += __shfl_xor(q2, 16, 64); q2 += __shfl_xor(q2, 32, 64);
        if (lane < 16) { red[w][16*st + r15][0] = s; red[w][16*st + r15][1] = q2; }
#pragma unroll
        for (int reg = 0; reg < 4; reg++)
            QKVF[(size_t)(r0 + 16*w + 4*quad + reg)*768 + g*256 + 16*st + r15] = acc[st][reg];
    }
    __syncthreads();
    {
        float s = red[0][t][0] + red[1][t][0] + red[2][t][0] + red[3][t][0];
        float q = red[0][t][1] + red[1][t][1] + red[2][t][1] + red[3][t][1];
        atomicAdd(&sums[1024 + g*512 + t], s);
        atomicAdd(&sums[1024 + g*512 + 256 + t], q);
    }
}

// ---------------------------------------------------------------- affine+relu+bf16 (inline qkv BN finalize): q/k row-major, v transposed
__global__ __launch_bounds__(256) void affine_qkv(const float* __restrict__ QKVF, const float* __restrict__ sums,
                                                  const float* __restrict__ g_q, const float* __restrict__ b_q,
                                                  const float* __restrict__ g_k, const float* __restrict__ b_k,
                                                  const float* __restrict__ g_v, const float* __restrict__ b_v,
                                                  ushort* __restrict__ qk, ushort* __restrict__ vt) {
    __shared__ float sts[6][256];
    __shared__ ushort tile[64][72];
    int t = threadIdx.x;
    {
        const float* gs[3] = {g_q, g_k, g_v};
        const float* bs[3] = {b_q, b_k, b_v};
#pragma unroll
        for (int g = 0; g < 3; g++) {
            float mean = sums[1024 + g*512 + t] * (1.0f/(float)ROWS);
            float var  = sums[1024 + g*512 + 256 + t] * (1.0f/(float)ROWS) - mean*mean;
            float sc = gs[g][t] / sqrtf(var + 1e-5f);
            sts[2*g][t] = sc;
            sts[2*g+1][t] = bs[g][t] - mean*sc;
        }
    }
    __syncthreads();
    int r0 = blockIdx.x * 64, c0 = blockIdx.y * 64;
    int b = r0 >> 11, nbase = r0 & 2047;
    if (c0 < 512) {
#pragma unroll
        for (int rep = 0; rep < 16; rep++) {
            int e = t + 256*rep;
            int row = e >> 6, c = e & 63;
            int col = c0 + c, g = col >> 8, cc = col & 255;
            float v = QKVF[(size_t)(r0 + row)*768 + col];
            v = fmaxf(fmaf(sts[2*g][cc], v, sts[2*g+1][cc]), 0.f);
            qk[(size_t)(r0 + row)*512 + col] = f2bf(v);
        }
    } else {
#pragma unroll
        for (int rep = 0; rep < 16; rep++) {
            int e = t + 256*rep;
            int row = e >> 6, c = e & 63;
            int col = c0 + c, cc = col & 255;
            float v = QKVF[(size_t)(r0 + row)*768 + col];
            v = fmaxf(fmaf(sts[4][cc], v, sts[5][cc]), 0.f);
            tile[c][row] = f2bf(v);
        }
        __syncthreads();
#pragma unroll
        for (int rep = 0; rep < 16; rep++) {
            int e = t + 256*rep;
            int cc = e >> 6, nn = e & 63;
            vt[((size_t)(b*256 + (c0 - 512) + cc))*2048 + nbase + nn] = tile[cc][nn];
        }
    }
}

// ---------------------------------------------------------------- MFMA bf16 flash attention, 2 Q-tiles/block, DPP softmax
__global__ __launch_bounds__(256) void attn2(const ushort* __restrict__ qk, const ushort* __restrict__ vt,
                                             float* __restrict__ obuf) {
    __shared__ ushort Ksh[64*72];
    __shared__ ushort Vts[64*72];
    __shared__ ushort Psh[128*72];
    int h = blockIdx.y, b = blockIdx.z;
    int r0 = blockIdx.x * 128;
    int t = threadIdx.x;
    int w = t >> 6, lane = t & 63;
    int r15 = lane & 15, quad = lane >> 4;
    size_t rowbase = (size_t)b*NPTS;
    int hoff = h*DSH;

    short8 aq[2][2];
#pragma unroll
    for (int u = 0; u < 2; u++)
#pragma unroll
        for (int s = 0; s < 2; s++)
            aq[u][s] = *(const short8*)(qk + (rowbase + r0 + 64*u + 16*w + r15)*512 + hoff + 32*s + 8*quad);

    floatx4 zero4 = {0.f, 0.f, 0.f, 0.f};
    floatx4 oacc[2][4];
    float mrun[2][4], lrun[2][4];
#pragma unroll
    for (int u = 0; u < 2; u++)
#pragma unroll
        for (int i = 0; i < 4; i++) { oacc[u][i] = zero4; mrun[u][i] = -1e30f; lrun[u][i] = 0.f; }

    for (int m0 = 0; m0 < NPTS; m0 += 64) {
#pragma unroll
        for (int rep = 0; rep < 2; rep++) {
            int e = t + 256*rep;
            int rr = e >> 3, c = e & 7;
            *(uint4*)&Ksh[rr*72 + 8*c] =
                *(const uint4*)(qk + (rowbase + m0 + rr)*512 + 256 + hoff + 8*c);
            *(uint4*)&Vts[rr*72 + 8*c] =
                *(const uint4*)(vt + ((size_t)(b*256 + hoff + rr))*2048 + m0 + 8*c);
        }
        __syncthreads();

        floatx4 sacc[2][4];
#pragma unroll
        for (int u = 0; u < 2; u++)
#pragma unroll
            for (int tt = 0; tt < 4; tt++) sacc[u][tt] = zero4;
#pragma unroll
        for (int tt = 0; tt < 4; tt++) {
            int key = 16*tt + r15;
#pragma unroll
            for (int s = 0; s < 2; s++) {
                short8 kf = *(const short8*)&Ksh[key*72 + 32*s + 8*quad];
#pragma unroll
                for (int u = 0; u < 2; u++)
                    sacc[u][tt] = __builtin_amdgcn_mfma_f32_16x16x32_bf16(aq[u][s], kf, sacc[u][tt], 0, 0, 0);
            }
        }

        float pm[2][4][4];
#pragma unroll
        for (int u = 0; u < 2; u++)
#pragma unroll
            for (int reg = 0; reg < 4; reg++) {
                float rmax = fmaxf(fmaxf(sacc[u][0][reg], sacc[u][1][reg]),
                                   fmaxf(sacc[u][2][reg], sacc[u][3][reg]));
                rmax = dpp_max16(rmax);
                float mnew = fmaxf(mrun[u][reg], rmax);
                float alpha = __expf(mrun[u][reg] - mnew);
                float rs = 0.f;
#pragma unroll
                for (int tt = 0; tt < 4; tt++) {
                    float p = __expf(sacc[u][tt][reg] - mnew);
                    pm[u][tt][reg] = p; rs += p;
                }
                rs = dpp_sum16(rs);
                lrun[u][reg] = lrun[u][reg]*alpha + rs;
                mrun[u][reg] = mnew;
#pragma unroll
                for (int td = 0; td < 4; td++) oacc[u][td][reg] *= alpha;
            }

#pragma unroll
        for (int u = 0; u < 2; u++)
#pragma unroll
            for (int reg = 0; reg < 4; reg++) {
                int row = 64*u + 16*w + 4*quad + reg;
#pragma unroll
                for (int tt = 0; tt < 4; tt++)
                    Psh[row*72 + 16*tt + r15] = f2bf(pm[u][tt][reg]);
            }
        __syncthreads();

#pragma unroll
        for (int s = 0; s < 2; s++) {
            short8 pf[2];
#pragma unroll
            for (int u = 0; u < 2; u++)
                pf[u] = *(const short8*)&Psh[(64*u + 16*w + r15)*72 + 32*s + 8*quad];
#pragma unroll
            for (int td = 0; td < 4; td++) {
                short8 vf = *(const short8*)&Vts[(16*td + r15)*72 + 32*s + 8*quad];
#pragma unroll
                for (int u = 0; u < 2; u++)
                    oacc[u][td] = __builtin_amdgcn_mfma_f32_16x16x32_bf16(pf[u], vf, oacc[u][td], 0, 0, 0);
            }
        }
        __syncthreads();
    }

#pragma unroll
    for (int u = 0; u < 2; u++)
#pragma unroll
        for (int reg = 0; reg < 4; reg++) {
            int grow = r0 + 64*u + 16*w + 4*quad + reg;
            float invl = 1.f / lrun[u][reg];
#pragma unroll
            for (int td = 0; td < 4; td++)
                obuf[(rowbase + grow)*(size_t)(NHEADS*WCH) + h*WCH + 16*td + r15] = oacc[u][td][reg]*invl;
        }
}

// ---------------------------------------------------------------- fus GEMM (bias, fp32 out, stats epilogue)
__global__ __launch_bounds__(256) void gemm_fus(const float* __restrict__ A, const float* __restrict__ W,
                                                const float* __restrict__ bias, float* __restrict__ C,
                                                float* __restrict__ sums) {
    __shared__ float As[16][68];
    __shared__ float Ws[16][68];
    __shared__ float red[4][64][2];
    int t = threadIdx.x;
    int tx = t & 15, ty = t >> 4;
    int r0 = blockIdx.x * 64, n0 = blockIdx.y * 64;
    float acc[4][4];
#pragma unroll
    for (int i = 0; i < 4; i++)
#pragma unroll
        for (int j = 0; j < 4; j++) acc[i][j] = 0.f;
    int lk = t & 15, lm = t >> 4;
    for (int k0 = 0; k0 < 448; k0 += 16) {
#pragma unroll
        for (int i2 = 0; i2 < 4; i2++) {
            As[lk][lm + 16*i2] = A[(size_t)(r0 + lm + 16*i2)*448 + k0 + lk];
            Ws[lk][lm + 16*i2] = W[(size_t)(n0 + lm + 16*i2)*448 + k0 + lk];
        }
        __syncthreads();
#pragma unroll
        for (int kq = 0; kq < 16; kq++) {
            float4 a  = *(const float4*)&As[kq][4*ty];
            float4 b4 = *(const float4*)&Ws[kq][4*tx];
            float av[4] = {a.x, a.y, a.z, a.w};
            float bv[4] = {b4.x, b4.y, b4.z, b4.w};
#pragma unroll
            for (int i = 0; i < 4; i++)
#pragma unroll
                for (int j = 0; j < 4; j++) acc[i][j] = fmaf(av[i], bv[j], acc[i][j]);
        }
        __syncthreads();
    }
    float ps[4], pss[4];
#pragma unroll
    for (int j = 0; j < 4; j++) { ps[j] = 0.f; pss[j] = 0.f; }
#pragma unroll
    for (int i = 0; i < 4; i++)
#pragma unroll
        for (int j = 0; j < 4; j++) {
            float v = acc[i][j] + bias[n0 + 4*tx + j];
            C[(size_t)(r0 + 4*ty + i)*256 + n0 + 4*tx + j] = v;
            ps[j] += v; pss[j] += v*v;
        }
#pragma unroll
    for (int j = 0; j < 4; j++) {
        ps[j]  += __shfl_xor(ps[j], 16, 64);  ps[j]  += __shfl_xor(ps[j], 32, 64);
        pss[j] += __shfl_xor(pss[j], 16, 64); pss[j] += __shfl_xor(pss[j], 32, 64);
    }
    int wv = t >> 6, lane = t & 63;
    if (lane < 16) {
#pragma unroll
        for (int j = 0; j < 4; j++) {
            red[wv][4*tx + j][0] = ps[j];
            red[wv][4*tx + j][1] = pss[j];
        }
    }
    __syncthreads();
    if (t < 128) {
        int col = t >> 1, which = t & 1;
        float v = red[0][col][which] + red[1][col][which] + red[2][col][which] + red[3][col][which];
        atomicAdd(&sums[2560 + which*256 + n0 + col], v);
    }
}

// ---------------------------------------------------------------- fused: inline fus-BN finalize + relu + residual + LayerNorm
__global__ __launch_bounds__(256) void ln_fused(float* __restrict__ fusp, const float* __restrict__ feature,
                                                const float* __restrict__ sums,
                                                const float* __restrict__ g_fus, const float* __restrict__ b_fus,
                                                const float* __restrict__ g_ln, const float* __restrict__ b_ln,
                                                float* __restrict__ y) {
    int r = blockIdx.x, c = threadIdx.x;
    float mean0 = sums[2560 + c] * (1.0f/(float)ROWS);
    float var0  = sums[2560 + 256 + c] * (1.0f/(float)ROWS) - mean0*mean0;
    float scF = g_fus[c] / sqrtf(var0 + 1e-5f);
    float shF = b_fus[c] - mean0*scF;
    size_t i = (size_t)r*256 + c;
    float fus = fmaxf(fmaf(scF, fusp[i], shF), 0.f);
    float v = fus + feature[i];
    float s = v, ss = v*v;
    for (int m = 1; m < 64; m <<= 1) { s += __shfl_xor(s, m, 64); ss += __shfl_xor(ss, m, 64); }
    __shared__ float red[8];
    int wave = c >> 6, lane = c & 63;
    if (lane == 0) { red[wave] = s; red[4+wave] = ss; }
    __syncthreads();
    s  = red[0]+red[1]+red[2]+red[3];
    ss = red[4]+red[5]+red[6]+red[7];
    float mean = s * (1.f/256.f);
    float var  = ss * (1.f/256.f) - mean*mean;
    float rin  = 1.f/sqrtf(var + 1e-5f);
    fusp[i] = v;
    y[i] = (v - mean)*rin*g_ln[c] + b_ln[c];
}

// ---------------------------------------------------------------- MLP GEMM + residual + transposed store to d_out
__global__ __launch_bounds__(256) void gemm_mlp(const float* __restrict__ A, const float* __restrict__ W,
                                                const float* __restrict__ bias, const float* __restrict__ FF,
                                                float* __restrict__ outp) {
    __shared__ float As[16][68];
    __shared__ float Ws[16][68];
    __shared__ float tr[64][65];
    int t = threadIdx.x;
    int tx = t & 15, ty = t >> 4;
    int r0 = blockIdx.x * 64, n0 = blockIdx.y * 64;
    float acc[4][4];
#pragma unroll
    for (int i = 0; i < 4; i++)
#pragma unroll
        for (int j = 0; j < 4; j++) acc[i][j] = 0.f;
    int lk = t & 15, lm = t >> 4;
    for (int k0 = 0; k0 < 256; k0 += 16) {
#pragma unroll
        for (int i2 = 0; i2 < 4; i2++) {
            As[lk][lm + 16*i2] = A[(size_t)(r0 + lm + 16*i2)*256 + k0 + lk];
            Ws[lk][lm + 16*i2] = W[(size_t)(n0 + lm + 16*i2)*256 + k0 + lk];
        }
        __syncthreads();
#pragma unroll
        for (int kq = 0; kq < 16; kq++) {
            float4 a  = *(const float4*)&As[kq][4*ty];
            float4 b4 = *(const float4*)&Ws[kq][4*tx];
            float av[4] = {a.x, a.y, a.z, a.w};
            float bv[4] = {b4.x, b4.y, b4.z, b4.w};
#pragma unroll
            for (int i = 0; i < 4; i++)
#pragma unroll
                for (int j = 0; j < 4; j++) acc[i][j] = fmaf(av[i], bv[j], acc[i][j]);
        }
        __syncthreads();
    }
#pragma unroll
    for (int i = 0; i < 4; i++)
#pragma unroll
        for (int j = 0; j < 4; j++) {
            float v = acc[i][j] + bias[n0 + 4*tx + j] + FF[(size_t)(r0 + 4*ty + i)*256 + n0 + 4*tx + j];
            tr[4*tx + j][4*ty + i] = v;
        }
    __syncthreads();
    int b = r0 >> 11, nbase = r0 & 2047;
#pragma unroll
    for (int rep = 0; rep < 16; rep++) {
        int e = t + 256*rep;
        int cl = e >> 6, nl = e & 63;
        outp[((size_t)(b*256 + n0 + cl))*2048 + nbase + nl] = tr[cl][nl];
    }
}

// ================================================================ host
extern "C" void kernel_launch(void* const* d_in, const int* in_sizes, int n_in,
                              void* d_out, int out_size, void* d_ws, size_t ws_size,
                              hipStream_t stream) {
    const float* xyz    = (const float*)d_in[0];
    const float* f      = (const float*)d_in[1];
    const float* W_geo  = (const float*)d_in[2];
    const float* g_geo  = (const float*)d_in[3];
    const float* b_geo  = (const float*)d_in[4];
    const float* W_feat = (const float*)d_in[5];
    const float* g_feat = (const float*)d_in[6];
    const float* b_feat = (const float*)d_in[7];
    const float* g_bn   = (const float*)d_in[8];
    const float* b_bn   = (const float*)d_in[9];
    const float* W_q    = (const float*)d_in[10];
    const float* g_q    = (const float*)d_in[11];
    const float* b_q    = (const float*)d_in[12];
    const float* W_k    = (const float*)d_in[13];
    const float* g_k    = (const float*)d_in[14];
    const float* b_k    = (const float*)d_in[15];
    const float* W_v    = (const float*)d_in[16];
    const float* g_v    = (const float*)d_in[17];
    const float* b_v    = (const float*)d_in[18];
    const float* W_fus  = (const float*)d_in[19];
    const float* bias_fus = (const float*)d_in[20];
    const float* g_fus  = (const float*)d_in[21];
    const float* b_fus  = (const float*)d_in[22];
    const float* g_ln   = (const float*)d_in[23];
    const float* b_ln   = (const float*)d_in[24];
    const float* W_mlp  = (const float*)d_in[25];
    const float* bias_mlp = (const float*)d_in[26];

    float* ws = (float*)d_ws;
    const size_t MBF = 262144;  // floats per MiB
    // Liveness (peak ~45.4 MiB):
    //  [0,1)    SUMS (3072f) + IDX (@16384f, 672KB)
    //  [1,9)    A: geoBC -> feature_ (live to ln_fused)
    //  [9,17)   X (featAC; dead after stats_gf) -> QK16 bf16 -> YB (y) after attn... (QK16 dead after attn? read by attn only) 
    //  [17,25)  CSEL (dead after maxsel)
    //  [17,41)  QKVF fp32 (over dead CSEL; dead after affine_qkv)
    //  [17,31)  OBUF fp32 (over dead QKVF; attn -> gemm_fus)
    //  [31,39)  FUSP fp32 (gemm_fus out -> feature__ in place)
    //  [41,45)  VT16 bf16
    //  [45,45.4) Wbf16 (3x256x256)
    float* SUMS  = ws;
    int*   IDX   = (int*)(ws + 16384);
    float* A     = ws + 1*MBF;
    float* X     = ws + 9*MBF;
    ushort* QK16 = (ushort*)(ws + 9*MBF);
    float* YB    = ws + 9*MBF;
    float* CSEL  = ws + 17*MBF;
    float* QKVF  = ws + 17*MBF;
    float* OBUF  = ws + 17*MBF;
    float* FUSP  = ws + 31*MBF;
    ushort* VT16 = (ushort*)(ws + 41*MBF);
    ushort* WB16 = (ushort*)(ws + 45*MBF);

    prep_kernel<<<dim3(128, 4), 256, 0, stream>>>(f, W_feat, xyz, W_geo, W_q, W_k, W_v,
                                                  X, A, WB16, SUMS);
    knn_kernel<<<ROWS/4, 256, 0, stream>>>(xyz, IDX);
    stats_gf<<<256, 256, 0, stream>>>(A, X, IDX, g_geo, g_feat, SUMS, CSEL);
    feature_maxsel<<<256, 256, 0, stream>>>(CSEL, SUMS, g_geo, b_geo, g_feat, b_feat, A, SUMS + 512);
    gemm_qkv<<<dim3(128, 3), 256, 0, stream>>>(A, SUMS, g_bn, b_bn, WB16, QKVF, SUMS);
    affine_qkv<<<dim3(128, 12), 256, 0, stream>>>(QKVF, SUMS, g_q, b_q, g_k, b_k, g_v, b_v, QK16, VT16);
    attn2<<<dim3(NPTS/128, NHEADS, NB), 256, 0, stream>>>(QK16, VT16, OBUF);
    gemm_fus<<<dim3(128, 4), 256, 0, stream>>>(OBUF, W_fus, bias_fus, FUSP, SUMS);
    ln_fused<<<ROWS, 256, 0, stream>>>(FUSP, A, SUMS, g_fus, b_fus, g_ln, b_ln, YB);
    gemm_mlp<<<dim3(128, 4), 256, 0, stream>>>(YB, W_mlp, bias_mlp, FUSP, (float*)d_out);
}

// Round 11
// 435.567 us; speedup vs baseline: 1.3478x; 1.1502x over previous
//
#include <hip/hip_runtime.h>
#include <math.h>

#define NB    4
#define NPTS  2048
#define ROWS  (NB*NPTS)   // 8192
#define CIN   64
#define COUT  256
#define KNBR  21
#define NHEADS 7
#define WCH   64
#define DSH   32

typedef __attribute__((ext_vector_type(8))) short short8;
typedef __attribute__((ext_vector_type(4))) float floatx4;

__device__ __forceinline__ ushort f2bf(float x) {
    unsigned u = __float_as_uint(x);
    u += 0x7fffu + ((u >> 16) & 1u);   // RNE
    return (ushort)(u >> 16);
}

// DPP rotate within 16-lane row (VALU, no LDS pipe)
template<int N>
__device__ __forceinline__ float dpp_ror16(float x) {
    return __int_as_float(__builtin_amdgcn_update_dpp(
        0, __float_as_int(x), 0x120 | N, 0xF, 0xF, true));
}
__device__ __forceinline__ float dpp_max16(float x) {
    x = fmaxf(x, dpp_ror16<1>(x));
    x = fmaxf(x, dpp_ror16<2>(x));
    x = fmaxf(x, dpp_ror16<4>(x));
    x = fmaxf(x, dpp_ror16<8>(x));
    return x;
}
__device__ __forceinline__ float dpp_sum16(float x) {
    x += dpp_ror16<1>(x);
    x += dpp_ror16<2>(x);
    x += dpp_ror16<4>(x);
    x += dpp_ror16<8>(x);
    return x;
}

// wave64 u32 min-reduce via canonical DPP chain; result broadcast via readlane(63)
template<int CTRL, int RMASK>
__device__ __forceinline__ unsigned dpp_umin_step(unsigned x) {
    unsigned t = (unsigned)__builtin_amdgcn_update_dpp((int)x, (int)x, CTRL, RMASK, 0xF, false);
    return (t < x) ? t : x;
}
__device__ __forceinline__ unsigned wave_min_u32(unsigned x) {
    x = dpp_umin_step<0x111, 0xF>(x);   // row_shr:1
    x = dpp_umin_step<0x112, 0xF>(x);   // row_shr:2
    x = dpp_umin_step<0x114, 0xF>(x);   // row_shr:4
    x = dpp_umin_step<0x118, 0xF>(x);   // row_shr:8
    x = dpp_umin_step<0x142, 0xA>(x);   // row_bcast:15
    x = dpp_umin_step<0x143, 0xC>(x);   // row_bcast:31
    return (unsigned)__builtin_amdgcn_readlane((int)x, 63);
}

// ---------------------------------------------------------------- fused prep (blocks 0..511) + KNN (blocks 512..2559)
// prep: featAC GEMM + geoBC + W->bf16 + zero SUMS
// knn:  fp32-filter top-32 (u32 keys, DPP reduce) + exact f64 refine (bitonic), 4 queries/block
__global__ __launch_bounds__(256) void prep_knn(const float* __restrict__ f, const float* __restrict__ Wf,
                                                const float* __restrict__ xyz, const float* __restrict__ Wg,
                                                const float* __restrict__ W_q, const float* __restrict__ W_k,
                                                const float* __restrict__ W_v,
                                                float* __restrict__ X, float* __restrict__ A,
                                                ushort* __restrict__ Wb, float* __restrict__ sums,
                                                int* __restrict__ idx) {
    __shared__ float4 SXQ[2048];                    // 32 KB, aliased by prep staging
    int t = threadIdx.x;
    int blk = blockIdx.x;
    if (blk < 512) {
        // ======== prep path ========
        float* As = (float*)SXQ;                    // [16][68]
        float* Ws = As + 16*68;                     // [16][68]
        int bx = blk & 127, by = blk >> 7;
        if (by == 0 && bx < 12) sums[bx*256 + t] = 0.f;
        int gid = (by*128 + bx)*256 + t;            // 0..131071
        for (int i = gid; i < 196608; i += 131072) {
            const float* Wsrc = (i < 65536) ? W_q : (i < 131072) ? W_k : W_v;
            Wb[i] = f2bf(Wsrc[i & 65535]);
        }
        int r0 = bx * 64, n0 = by * 64;
        for (int e = t; e < 4096; e += 256) {
            int row = r0 + (e >> 6), c = n0 + (e & 63), cc = c & 127;
            float x = xyz[row*3], y = xyz[row*3+1], z = xyz[row*3+2];
            const float* w = Wg + cc*6;
            float s = (c < 128) ? ((w[3]*x + w[4]*y) + w[5]*z)
                                : (((w[0]-w[3])*x + (w[1]-w[4])*y) + (w[2]-w[5])*z);
            A[(size_t)row*256 + c] = s;
        }
        int b = r0 >> 11, nbase = r0 & 2047;
        int tx = t & 15, ty = t >> 4;
        float acc[4][4];
#pragma unroll
        for (int i = 0; i < 4; i++)
#pragma unroll
            for (int j = 0; j < 4; j++) acc[i][j] = 0.f;
        int m64 = t & 63, kg = t >> 6;
        int lk = t & 15, lm = t >> 4;
        for (int k0 = 0; k0 < 64; k0 += 16) {
#pragma unroll
            for (int p = 0; p < 4; p++) {
                int k = kg*4 + p;
                As[k*68 + m64] = f[(size_t)b*CIN*NPTS + (size_t)(k0 + k)*NPTS + nbase + m64];
            }
#pragma unroll
            for (int i2 = 0; i2 < 4; i2++) {
                int cg = n0 + lm + 16*i2;
                Ws[lk*68 + lm + 16*i2] = Wf[(size_t)(cg & 127)*128 + (cg >> 7)*64 + k0 + lk];
            }
            __syncthreads();
#pragma unroll
            for (int kq = 0; kq < 16; kq++) {
                float4 a  = *(const float4*)&As[kq*68 + 4*ty];
                float4 b4 = *(const float4*)&Ws[kq*68 + 4*tx];
                float av[4] = {a.x, a.y, a.z, a.w};
                float bv[4] = {b4.x, b4.y, b4.z, b4.w};
#pragma unroll
                for (int i = 0; i < 4; i++)
#pragma unroll
                    for (int j = 0; j < 4; j++) acc[i][j] = fmaf(av[i], bv[j], acc[i][j]);
            }
            __syncthreads();
        }
#pragma unroll
        for (int i = 0; i < 4; i++)
#pragma unroll
            for (int j = 0; j < 4; j++)
                X[(size_t)(r0 + 4*ty + i)*256 + n0 + 4*tx + j] = acc[i][j];
        return;
    }
    // ======== KNN path ========
    int kb = blk - 512;
    int b = kb >> 9;            // batch
    int g = kb & 511;           // query group (4 queries)
    for (int m = t; m < NPTS; m += 256) {
        float x = xyz[(size_t)b*NPTS*3 + m*3];
        float y = xyz[(size_t)b*NPTS*3 + m*3 + 1];
        float z = xyz[(size_t)b*NPTS*3 + m*3 + 2];
        SXQ[m] = make_float4(x, y, z, (x*x + y*y) + z*z);
    }
    __syncthreads();
    int w = t >> 6, lane = t & 63;
    int n = g*4 + w;
    float4 q4 = SXQ[n];
    float qx = q4.x, qy = q4.y, qz = q4.z, sqn = q4.w;
    // fp32 filter keys: (d2bits & ~2047) | m
    unsigned key[32];
#pragma unroll
    for (int i = 0; i < 32; i++) {
        int m = lane + (i << 6);
        float4 p = SXQ[m];
        float dt = (qx*p.x + qy*p.y) + qz*p.z;
        float d2 = fmaxf((sqn + p.w) - 2.0f*dt, 0.f);
        key[i] = (__float_as_uint(d2) & 0xFFFFF800u) | (unsigned)m;
    }
    // extract top-32 approx
    unsigned winkey = 0xFFFFFFFFu;
    for (int kk = 0; kk < 32; kk++) {
        unsigned lv = key[0];
#pragma unroll
        for (int i = 1; i < 32; i++) lv = (key[i] < lv) ? key[i] : lv;
        unsigned win = wave_min_u32(lv);
        if (lane == kk) winkey = win;
        unsigned widx = win & 2047u;
        int slot = (int)(widx >> 6);
        bool own = (lane == (int)(widx & 63u));
#pragma unroll
        for (int i = 0; i < 32; i++)
            if (i == slot && own) key[i] = 0xFFFFFFFFu;
    }
    // exact f64 refine of the 32 survivors (lanes 0..31); lanes 32..63 pad +inf
    double d2r;
    int mr;
    {
        double qx64 = (double)qx, qy64 = (double)qy, qz64 = (double)qz;
        double sqn64 = qx64*qx64 + qy64*qy64 + qz64*qz64;
        if (lane < 32) {
            mr = (int)(winkey & 2047u);
            float4 p = SXQ[mr];
            double x = (double)p.x, y = (double)p.y, z = (double)p.z;
            double sqm = x*x + y*y + z*z;
            double dt  = qx64*x + qy64*y + qz64*z;
            d2r = (sqn64 + sqm) - 2.0*dt;
        } else {
            d2r = INFINITY; mr = 0x7FFFFFFF;
        }
    }
    // bitonic ascending sort of (d2r, mr) across 32 lanes (lex order, idx tiebreak)
#pragma unroll
    for (int k = 2; k <= 32; k <<= 1) {
#pragma unroll
        for (int j = k >> 1; j > 0; j >>= 1) {
            double od = __shfl_xor(d2r, j, 64);
            int    om = __shfl_xor(mr, j, 64);
            bool up    = ((lane & k) == 0);
            bool lower = ((lane & j) == 0);
            bool oless = (od < d2r) || (od == d2r && om < mr);
            bool keepOther = up ? (lower ? oless : !oless) : (lower ? !oless : oless);
            if (keepOther) { d2r = od; mr = om; }
        }
    }
    if (lane < KNBR)
        idx[((size_t)b*NPTS + n)*KNBR + lane] = mr;
}

// ---------------------------------------------------------------- stats + sign-selected extreme over K
__global__ __launch_bounds__(256) void stats_gf(const float* __restrict__ geoBC, const float* __restrict__ featAC,
                                                const int* __restrict__ idx, const float* __restrict__ g_geo,
                                                const float* __restrict__ g_feat,
                                                float* __restrict__ sums, float* __restrict__ xsel) {
    int c = threadIdx.x;
    int cc = c & 127;
    const float* base = (c < 128) ? geoBC : featAC;
    bool wantmax = ((c < 128) ? g_geo[cc] : g_feat[cc]) >= 0.f;
    float s = 0.f, ss = 0.f;
    int r0 = blockIdx.x * 32;
    for (int r = r0; r < r0 + 32; r++) {
        int b = r >> 11;
        float ctr = base[(size_t)r*256 + 128 + cc];
        float mx = -1e30f, mn = 1e30f;
        const int* ip = idx + (size_t)r*KNBR;
        for (int kk = 0; kk < KNBR; kk++) {
            int j = ip[kk];
            float xv = ctr + base[((size_t)(b*NPTS + j))*256 + cc];
            mx = fmaxf(mx, xv); mn = fminf(mn, xv);
            s += xv; ss += xv*xv;
        }
        xsel[(size_t)r*256 + c] = wantmax ? mx : mn;
    }
    atomicAdd(&sums[c], s);
    atomicAdd(&sums[256 + c], ss);
}

// ---------------------------------------------------------------- feature_ = relu(affine(xsel)) with inline BN finalize; + bn1 stats
__global__ __launch_bounds__(256) void feature_maxsel(const float* __restrict__ xsel, const float* __restrict__ sums,
                                                      const float* __restrict__ g_geo, const float* __restrict__ b_geo,
                                                      const float* __restrict__ g_feat, const float* __restrict__ b_feat,
                                                      float* __restrict__ feat, float* __restrict__ sums_bn1) {
    int c = threadIdx.x;
    const float inv = 1.0f / (float)(ROWS*KNBR);
    float mean = sums[c]*inv;
    float var  = sums[256+c]*inv - mean*mean;
    float g  = (c < 128) ? g_geo[c] : g_feat[c-128];
    float bb = (c < 128) ? b_geo[c] : b_feat[c-128];
    float sc = g / sqrtf(var + 1e-5f);
    float tt = bb - mean*sc;
    float s = 0.f, ss = 0.f;
    int r0 = blockIdx.x*32;
    for (int r = r0; r < r0+32; r++) {
        size_t i = (size_t)r*256 + c;
        float y = fmaxf(fmaf(sc, xsel[i], tt), 0.f);
        feat[i] = y; s += y; ss += y*y;
    }
    atomicAdd(&sums_bn1[c], s); atomicAdd(&sums_bn1[256+c], ss);
}

// ---------------------------------------------------------------- q/k/v GEMM via bf16 MFMA; inline bn1 finalize on A
__global__ __launch_bounds__(256) void gemm_qkv(const float* __restrict__ Af, const float* __restrict__ sums_in,
                                                const float* __restrict__ g_bn, const float* __restrict__ b_bn,
                                                const ushort* __restrict__ Wb,
                                                float* __restrict__ QKVF, float* __restrict__ sums) {
    __shared__ float bns[2][256];
    __shared__ float red[4][256][2];
    int t = threadIdx.x;
    int r0 = blockIdx.x * 64, g = blockIdx.y;
    int w = t >> 6, lane = t & 63;
    int r15 = lane & 15, quad = lane >> 4;
    {
        float mean = sums_in[512 + t] * (1.0f/(float)ROWS);
        float var  = sums_in[768 + t] * (1.0f/(float)ROWS) - mean*mean;
        float sc = g_bn[t] / sqrtf(var + 1e-5f);
        bns[0][t] = sc;
        bns[1][t] = b_bn[t] - mean*sc;
    }
    __syncthreads();
    short8 aq[8];
    {
        const float* ap = Af + (size_t)(r0 + 16*w + r15)*256;
#pragma unroll
        for (int kc = 0; kc < 8; kc++) {
            int k0 = 32*kc + 8*quad;
            float4 a0 = *(const float4*)&ap[k0];
            float4 a1 = *(const float4*)&ap[k0+4];
            float4 s0 = *(const float4*)&bns[0][k0];
            float4 s1 = *(const float4*)&bns[0][k0+4];
            float4 h0 = *(const float4*)&bns[1][k0];
            float4 h1 = *(const float4*)&bns[1][k0+4];
            ushort u8[8];
            u8[0] = f2bf(fmaf(s0.x, a0.x, h0.x)); u8[1] = f2bf(fmaf(s0.y, a0.y, h0.y));
            u8[2] = f2bf(fmaf(s0.z, a0.z, h0.z)); u8[3] = f2bf(fmaf(s0.w, a0.w, h0.w));
            u8[4] = f2bf(fmaf(s1.x, a1.x, h1.x)); u8[5] = f2bf(fmaf(s1.y, a1.y, h1.y));
            u8[6] = f2bf(fmaf(s1.z, a1.z, h1.z)); u8[7] = f2bf(fmaf(s1.w, a1.w, h1.w));
            aq[kc] = *(short8*)u8;
        }
    }
    floatx4 zero4 = {0.f, 0.f, 0.f, 0.f};
    floatx4 acc[16];
#pragma unroll
    for (int st = 0; st < 16; st++) acc[st] = zero4;
    const ushort* wbase = Wb + (size_t)g*65536 + (size_t)r15*256 + 8*quad;
#pragma unroll
    for (int st = 0; st < 16; st++) {
        const ushort* wp = wbase + (size_t)(16*st)*256;
#pragma unroll
        for (int kc = 0; kc < 8; kc++) {
            short8 bf = *(const short8*)(wp + 32*kc);
            acc[st] = __builtin_amdgcn_mfma_f32_16x16x32_bf16(aq[kc], bf, acc[st], 0, 0, 0);
        }
    }
#pragma unroll
    for (int st = 0; st < 16; st++) {
        float s  = (acc[st][0] + acc[st][1]) + (acc[st][2] + acc[st][3]);
        float q2 = (acc[st][0]*acc[st][0] + acc[st][1]*acc[st][1]) +
                   (acc[st][2]*acc[st][2] + acc[st][3]*acc[st][3]);
        s  += __shfl_xor(s, 16, 64);  s  += __shfl_xor(s, 32, 64);
        q2 += __shfl_xor(q2, 16, 64); q2 += __shfl_xor(q2, 32, 64);
        if (lane < 16) { red[w][16*st + r15][0] = s; red[w][16*st + r15][1] = q2; }
#pragma unroll
        for (int reg = 0; reg < 4; reg++)
            QKVF[(size_t)(r0 + 16*w + 4*quad + reg)*768 + g*256 + 16*st + r15] = acc[st][reg];
    }
    __syncthreads();
    {
        float s = red[0][t][0] + red[1][t][0] + red[2][t][0] + red[3][t][0];
        float q = red[0][t][1] + red[1][t][1] + red[2][t][1] + red[3][t][1];
        atomicAdd(&sums[1024 + g*512 + t], s);
        atomicAdd(&sums[1024 + g*512 + 256 + t], q);
    }
}

// ---------------------------------------------------------------- affine+relu+bf16 (inline qkv BN finalize): q/k row-major, v transposed
__global__ __launch_bounds__(256) void affine_qkv(const float* __restrict__ QKVF, const float* __restrict__ sums,
                                                  const float* __restrict__ g_q, const float* __restrict__ b_q,
                                                  const float* __restrict__ g_k, const float* __restrict__ b_k,
                                                  const float* __restrict__ g_v, const float* __restrict__ b_v,
                                                  ushort* __restrict__ qk, ushort* __restrict__ vt) {
    __shared__ float sts[6][256];
    __shared__ ushort tile[64][72];
    int t = threadIdx.x;
    {
        const float* gs[3] = {g_q, g_k, g_v};
        const float* bs[3] = {b_q, b_k, b_v};
#pragma unroll
        for (int g = 0; g < 3; g++) {
            float mean = sums[1024 + g*512 + t] * (1.0f/(float)ROWS);
            float var  = sums[1024 + g*512 + 256 + t] * (1.0f/(float)ROWS) - mean*mean;
            float sc = gs[g][t] / sqrtf(var + 1e-5f);
            sts[2*g][t] = sc;
            sts[2*g+1][t] = bs[g][t] - mean*sc;
        }
    }
    __syncthreads();
    int r0 = blockIdx.x * 64, c0 = blockIdx.y * 64;
    int b = r0 >> 11, nbase = r0 & 2047;
    if (c0 < 512) {
#pragma unroll
        for (int rep = 0; rep < 16; rep++) {
            int e = t + 256*rep;
            int row = e >> 6, c = e & 63;
            int col = c0 + c, g = col >> 8, cc = col & 255;
            float v = QKVF[(size_t)(r0 + row)*768 + col];
            v = fmaxf(fmaf(sts[2*g][cc], v, sts[2*g+1][cc]), 0.f);
            qk[(size_t)(r0 + row)*512 + col] = f2bf(v);
        }
    } else {
#pragma unroll
        for (int rep = 0; rep < 16; rep++) {
            int e = t + 256*rep;
            int row = e >> 6, c = e & 63;
            int col = c0 + c, cc = col & 255;
            float v = QKVF[(size_t)(r0 + row)*768 + col];
            v = fmaxf(fmaf(sts[4][cc], v, sts[5][cc]), 0.f);
            tile[c][row] = f2bf(v);
        }
        __syncthreads();
#pragma unroll
        for (int rep = 0; rep < 16; rep++) {
            int e = t + 256*rep;
            int cc = e >> 6, nn = e & 63;
            vt[((size_t)(b*256 + (c0 - 512) + cc))*2048 + nbase + nn] = tile[cc][nn];
        }
    }
}

// ---------------------------------------------------------------- MFMA bf16 flash attention, 2 Q-tiles/block, DPP softmax
__global__ __launch_bounds__(256) void attn2(const ushort* __restrict__ qk, const ushort* __restrict__ vt,
                                             float* __restrict__ obuf) {
    __shared__ ushort Ksh[64*72];
    __shared__ ushort Vts[64*72];
    __shared__ ushort Psh[128*72];
    int h = blockIdx.y, b = blockIdx.z;
    int r0 = blockIdx.x * 128;
    int t = threadIdx.x;
    int w = t >> 6, lane = t & 63;
    int r15 = lane & 15, quad = lane >> 4;
    size_t rowbase = (size_t)b*NPTS;
    int hoff = h*DSH;

    short8 aq[2][2];
#pragma unroll
    for (int u = 0; u < 2; u++)
#pragma unroll
        for (int s = 0; s < 2; s++)
            aq[u][s] = *(const short8*)(qk + (rowbase + r0 + 64*u + 16*w + r15)*512 + hoff + 32*s + 8*quad);

    floatx4 zero4 = {0.f, 0.f, 0.f, 0.f};
    floatx4 oacc[2][4];
    float mrun[2][4], lrun[2][4];
#pragma unroll
    for (int u = 0; u < 2; u++)
#pragma unroll
        for (int i = 0; i < 4; i++) { oacc[u][i] = zero4; mrun[u][i] = -1e30f; lrun[u][i] = 0.f; }

    for (int m0 = 0; m0 < NPTS; m0 += 64) {
#pragma unroll
        for (int rep = 0; rep < 2; rep++) {
            int e = t + 256*rep;
            int rr = e >> 3, c = e & 7;
            *(uint4*)&Ksh[rr*72 + 8*c] =
                *(const uint4*)(qk + (rowbase + m0 + rr)*512 + 256 + hoff + 8*c);
            *(uint4*)&Vts[rr*72 + 8*c] =
                *(const uint4*)(vt + ((size_t)(b*256 + hoff + rr))*2048 + m0 + 8*c);
        }
        __syncthreads();

        floatx4 sacc[2][4];
#pragma unroll
        for (int u = 0; u < 2; u++)
#pragma unroll
            for (int tt = 0; tt < 4; tt++) sacc[u][tt] = zero4;
#pragma unroll
        for (int tt = 0; tt < 4; tt++) {
            int key = 16*tt + r15;
#pragma unroll
            for (int s = 0; s < 2; s++) {
                short8 kf = *(const short8*)&Ksh[key*72 + 32*s + 8*quad];
#pragma unroll
                for (int u = 0; u < 2; u++)
                    sacc[u][tt] = __builtin_amdgcn_mfma_f32_16x16x32_bf16(aq[u][s], kf, sacc[u][tt], 0, 0, 0);
            }
        }

        float pm[2][4][4];
#pragma unroll
        for (int u = 0; u < 2; u++)
#pragma unroll
            for (int reg = 0; reg < 4; reg++) {
                float rmax = fmaxf(fmaxf(sacc[u][0][reg], sacc[u][1][reg]),
                                   fmaxf(sacc[u][2][reg], sacc[u][3][reg]));
                rmax = dpp_max16(rmax);
                float mnew = fmaxf(mrun[u][reg], rmax);
                float alpha = __expf(mrun[u][reg] - mnew);
                float rs = 0.f;
#pragma unroll
                for (int tt = 0; tt < 4; tt++) {
                    float p = __expf(sacc[u][tt][reg] - mnew);
                    pm[u][tt][reg] = p; rs += p;
                }
                rs = dpp_sum16(rs);
                lrun[u][reg] = lrun[u][reg]*alpha + rs;
                mrun[u][reg] = mnew;
#pragma unroll
                for (int td = 0; td < 4; td++) oacc[u][td][reg] *= alpha;
            }

#pragma unroll
        for (int u = 0; u < 2; u++)
#pragma unroll
            for (int reg = 0; reg < 4; reg++) {
                int row = 64*u + 16*w + 4*quad + reg;
#pragma unroll
                for (int tt = 0; tt < 4; tt++)
                    Psh[row*72 + 16*tt + r15] = f2bf(pm[u][tt][reg]);
            }
        __syncthreads();

#pragma unroll
        for (int s = 0; s < 2; s++) {
            short8 pf[2];
#pragma unroll
            for (int u = 0; u < 2; u++)
                pf[u] = *(const short8*)&Psh[(64*u + 16*w + r15)*72 + 32*s + 8*quad];
#pragma unroll
            for (int td = 0; td < 4; td++) {
                short8 vf = *(const short8*)&Vts[(16*td + r15)*72 + 32*s + 8*quad];
#pragma unroll
                for (int u = 0; u < 2; u++)
                    oacc[u][td] = __builtin_amdgcn_mfma_f32_16x16x32_bf16(pf[u], vf, oacc[u][td], 0, 0, 0);
            }
        }
        __syncthreads();
    }

#pragma unroll
    for (int u = 0; u < 2; u++)
#pragma unroll
        for (int reg = 0; reg < 4; reg++) {
            int grow = r0 + 64*u + 16*w + 4*quad + reg;
            float invl = 1.f / lrun[u][reg];
#pragma unroll
            for (int td = 0; td < 4; td++)
                obuf[(rowbase + grow)*(size_t)(NHEADS*WCH) + h*WCH + 16*td + r15] = oacc[u][td][reg]*invl;
        }
}

// ---------------------------------------------------------------- fus GEMM (bias, fp32 out, stats epilogue)
__global__ __launch_bounds__(256) void gemm_fus(const float* __restrict__ A, const float* __restrict__ W,
                                                const float* __restrict__ bias, float* __restrict__ C,
                                                float* __restrict__ sums) {
    __shared__ float As[16][68];
    __shared__ float Ws[16][68];
    __shared__ float red[4][64][2];
    int t = threadIdx.x;
    int tx = t & 15, ty = t >> 4;
    int r0 = blockIdx.x * 64, n0 = blockIdx.y * 64;
    float acc[4][4];
#pragma unroll
    for (int i = 0; i < 4; i++)
#pragma unroll
        for (int j = 0; j < 4; j++) acc[i][j] = 0.f;
    int lk = t & 15, lm = t >> 4;
    for (int k0 = 0; k0 < 448; k0 += 16) {
#pragma unroll
        for (int i2 = 0; i2 < 4; i2++) {
            As[lk][lm + 16*i2] = A[(size_t)(r0 + lm + 16*i2)*448 + k0 + lk];
            Ws[lk][lm + 16*i2] = W[(size_t)(n0 + lm + 16*i2)*448 + k0 + lk];
        }
        __syncthreads();
#pragma unroll
        for (int kq = 0; kq < 16; kq++) {
            float4 a  = *(const float4*)&As[kq][4*ty];
            float4 b4 = *(const float4*)&Ws[kq][4*tx];
            float av[4] = {a.x, a.y, a.z, a.w};
            float bv[4] = {b4.x, b4.y, b4.z, b4.w};
#pragma unroll
            for (int i = 0; i < 4; i++)
#pragma unroll
                for (int j = 0; j < 4; j++) acc[i][j] = fmaf(av[i], bv[j], acc[i][j]);
        }
        __syncthreads();
    }
    float ps[4], pss[4];
#pragma unroll
    for (int j = 0; j < 4; j++) { ps[j] = 0.f; pss[j] = 0.f; }
#pragma unroll
    for (int i = 0; i < 4; i++)
#pragma unroll
        for (int j = 0; j < 4; j++) {
            float v = acc[i][j] + bias[n0 + 4*tx + j];
            C[(size_t)(r0 + 4*ty + i)*256 + n0 + 4*tx + j] = v;
            ps[j] += v; pss[j] += v*v;
        }
#pragma unroll
    for (int j = 0; j < 4; j++) {
        ps[j]  += __shfl_xor(ps[j], 16, 64);  ps[j]  += __shfl_xor(ps[j], 32, 64);
        pss[j] += __shfl_xor(pss[j], 16, 64); pss[j] += __shfl_xor(pss[j], 32, 64);
    }
    int wv = t >> 6, lane = t & 63;
    if (lane < 16) {
#pragma unroll
        for (int j = 0; j < 4; j++) {
            red[wv][4*tx + j][0] = ps[j];
            red[wv][4*tx + j][1] = pss[j];
        }
    }
    __syncthreads();
    if (t < 128) {
        int col = t >> 1, which = t & 1;
        float v = red[0][col][which] + red[1][col][which] + red[2][col][which] + red[3][col][which];
        atomicAdd(&sums[2560 + which*256 + n0 + col], v);
    }
}

// ---------------------------------------------------------------- fused: inline fus-BN finalize + relu + residual + LayerNorm
__global__ __launch_bounds__(256) void ln_fused(float* __restrict__ fusp, const float* __restrict__ feature,
                                                const float* __restrict__ sums,
                                                const float* __restrict__ g_fus, const float* __restrict__ b_fus,
                                                const float* __restrict__ g_ln, const float* __restrict__ b_ln,
                                                float* __restrict__ y) {
    int r = blockIdx.x, c = threadIdx.x;
    float mean0 = sums[2560 + c] * (1.0f/(float)ROWS);
    float var0  = sums[2560 + 256 + c] * (1.0f/(float)ROWS) - mean0*mean0;
    float scF = g_fus[c] / sqrtf(var0 + 1e-5f);
    float shF = b_fus[c] - mean0*scF;
    size_t i = (size_t)r*256 + c;
    float fus = fmaxf(fmaf(scF, fusp[i], shF), 0.f);
    float v = fus + feature[i];
    float s = v, ss = v*v;
    for (int m = 1; m < 64; m <<= 1) { s += __shfl_xor(s, m, 64); ss += __shfl_xor(ss, m, 64); }
    __shared__ float red[8];
    int wave = c >> 6, lane = c & 63;
    if (lane == 0) { red[wave] = s; red[4+wave] = ss; }
    __syncthreads();
    s  = red[0]+red[1]+red[2]+red[3];
    ss = red[4]+red[5]+red[6]+red[7];
    float mean = s * (1.f/256.f);
    float var  = ss * (1.f/256.f) - mean*mean;
    float rin  = 1.f/sqrtf(var + 1e-5f);
    fusp[i] = v;
    y[i] = (v - mean)*rin*g_ln[c] + b_ln[c];
}

// ---------------------------------------------------------------- MLP GEMM + residual + transposed store to d_out
__global__ __launch_bounds__(256) void gemm_mlp(const float* __restrict__ A, const float* __restrict__ W,
                                                const float* __restrict__ bias, const float* __restrict__ FF,
                                                float* __restrict__ outp) {
    __shared__ float As[16][68];
    __shared__ float Ws[16][68];
    __shared__ float tr[64][65];
    int t = threadIdx.x;
    int tx = t & 15, ty = t >> 4;
    int r0 = blockIdx.x * 64, n0 = blockIdx.y * 64;
    float acc[4][4];
#pragma unroll
    for (int i = 0; i < 4; i++)
#pragma unroll
        for (int j = 0; j < 4; j++) acc[i][j] = 0.f;
    int lk = t & 15, lm = t >> 4;
    for (int k0 = 0; k0 < 256; k0 += 16) {
#pragma unroll
        for (int i2 = 0; i2 < 4; i2++) {
            As[lk][lm + 16*i2] = A[(size_t)(r0 + lm + 16*i2)*256 + k0 + lk];
            Ws[lk][lm + 16*i2] = W[(size_t)(n0 + lm + 16*i2)*256 + k0 + lk];
        }
        __syncthreads();
#pragma unroll
        for (int kq = 0; kq < 16; kq++) {
            float4 a  = *(const float4*)&As[kq][4*ty];
            float4 b4 = *(const float4*)&Ws[kq][4*tx];
            float av[4] = {a.x, a.y, a.z, a.w};
            float bv[4] = {b4.x, b4.y, b4.z, b4.w};
#pragma unroll
            for (int i = 0; i < 4; i++)
#pragma unroll
                for (int j = 0; j < 4; j++) acc[i][j] = fmaf(av[i], bv[j], acc[i][j]);
        }
        __syncthreads();
    }
#pragma unroll
    for (int i = 0; i < 4; i++)
#pragma unroll
        for (int j = 0; j < 4; j++) {
            float v = acc[i][j] + bias[n0 + 4*tx + j] + FF[(size_t)(r0 + 4*ty + i)*256 + n0 + 4*tx + j];
            tr[4*tx + j][4*ty + i] = v;
        }
    __syncthreads();
    int b = r0 >> 11, nbase = r0 & 2047;
#pragma unroll
    for (int rep = 0; rep < 16; rep++) {
        int e = t + 256*rep;
        int cl = e >> 6, nl = e & 63;
        outp[((size_t)(b*256 + n0 + cl))*2048 + nbase + nl] = tr[cl][nl];
    }
}

// ================================================================ host
extern "C" void kernel_launch(void* const* d_in, const int* in_sizes, int n_in,
                              void* d_out, int out_size, void* d_ws, size_t ws_size,
                              hipStream_t stream) {
    const float* xyz    = (const float*)d_in[0];
    const float* f      = (const float*)d_in[1];
    const float* W_geo  = (const float*)d_in[2];
    const float* g_geo  = (const float*)d_in[3];
    const float* b_geo  = (const float*)d_in[4];
    const float* W_feat = (const float*)d_in[5];
    const float* g_feat = (const float*)d_in[6];
    const float* b_feat = (const float*)d_in[7];
    const float* g_bn   = (const float*)d_in[8];
    const float* b_bn   = (const float*)d_in[9];
    const float* W_q    = (const float*)d_in[10];
    const float* g_q    = (const float*)d_in[11];
    const float* b_q    = (const float*)d_in[12];
    const float* W_k    = (const float*)d_in[13];
    const float* g_k    = (const float*)d_in[14];
    const float* b_k    = (const float*)d_in[15];
    const float* W_v    = (const float*)d_in[16];
    const float* g_v    = (const float*)d_in[17];
    const float* b_v    = (const float*)d_in[18];
    const float* W_fus  = (const float*)d_in[19];
    const float* bias_fus = (const float*)d_in[20];
    const float* g_fus  = (const float*)d_in[21];
    const float* b_fus  = (const float*)d_in[22];
    const float* g_ln   = (const float*)d_in[23];
    const float* b_ln   = (const float*)d_in[24];
    const float* W_mlp  = (const float*)d_in[25];
    const float* bias_mlp = (const float*)d_in[26];

    float* ws = (float*)d_ws;
    const size_t MBF = 262144;  // floats per MiB
    float* SUMS  = ws;
    int*   IDX   = (int*)(ws + 16384);
    float* A     = ws + 1*MBF;
    float* X     = ws + 9*MBF;
    ushort* QK16 = (ushort*)(ws + 9*MBF);
    float* YB    = ws + 9*MBF;
    float* CSEL  = ws + 17*MBF;
    float* QKVF  = ws + 17*MBF;
    float* OBUF  = ws + 17*MBF;
    float* FUSP  = ws + 31*MBF;
    ushort* VT16 = (ushort*)(ws + 41*MBF);
    ushort* WB16 = (ushort*)(ws + 45*MBF);

    prep_knn<<<2560, 256, 0, stream>>>(f, W_feat, xyz, W_geo, W_q, W_k, W_v,
                                       X, A, WB16, SUMS, IDX);
    stats_gf<<<256, 256, 0, stream>>>(A, X, IDX, g_geo, g_feat, SUMS, CSEL);
    feature_maxsel<<<256, 256, 0, stream>>>(CSEL, SUMS, g_geo, b_geo, g_feat, b_feat, A, SUMS + 512);
    gemm_qkv<<<dim3(128, 3), 256, 0, stream>>>(A, SUMS, g_bn, b_bn, WB16, QKVF, SUMS);
    affine_qkv<<<dim3(128, 12), 256, 0, stream>>>(QKVF, SUMS, g_q, b_q, g_k, b_k, g_v, b_v, QK16, VT16);
    attn2<<<dim3(NPTS/128, NHEADS, NB), 256, 0, stream>>>(QK16, VT16, OBUF);
    gemm_fus<<<dim3(128, 4), 256, 0, stream>>>(OBUF, W_fus, bias_fus, FUSP, SUMS);
    ln_fused<<<ROWS, 256, 0, stream>>>(FUSP, A, SUMS, g_fus, b_fus, g_ln, b_ln, YB);
    gemm_mlp<<<dim3(128, 4), 256, 0, stream>>>(YB, W_mlp, bias_mlp, FUSP, (float*)d_out);
}